// Round 8
// baseline (1131.681 us; speedup 1.0000x reference)
//
#include <hip/hip_runtime.h>
#include <math.h>

#define BB 4
#define SS 256
#define DD 300
#define DP 304   // DD padded to multiple of 16
#define EE 128
#define LL 20
#define H3 384
#define D2 256   // 2E
#define D12 1536 // 12E

typedef __attribute__((ext_vector_type(8)))  short short8;
typedef __attribute__((ext_vector_type(16))) float f32x16;
typedef __attribute__((ext_vector_type(2)))  float f32x2;

__device__ __forceinline__ float tanh_fast(float x){
  float e = __expf(2.f*x);
  return 1.f - 2.f/(e+1.f);
}
__device__ __forceinline__ float sigmoidf_(float x){ return 1.f/(1.f+__expf(-x)); }
__device__ __forceinline__ float bf16_to_f(unsigned u){ return __builtin_bit_cast(float, u<<16); }
__device__ __forceinline__ float bf16hi_to_f(unsigned u){ return __builtin_bit_cast(float, u & 0xFFFF0000u); }
__device__ __forceinline__ unsigned bf16_rne(float f){
  unsigned u = __builtin_bit_cast(unsigned, f);
  return (u + 0x7FFFu + ((u>>16)&1u)) >> 16;
}
__device__ __forceinline__ unsigned pack_bf16x2(float lo, float hi){
  return bf16_rne(lo) | (bf16_rne(hi)<<16);
}

__device__ __forceinline__ float wred_max(float v){
  #pragma unroll
  for (int st=1; st<64; st<<=1) v = fmaxf(v, __shfl_xor(v, st));
  return v;
}
__device__ __forceinline__ float wred_sum(float v){
  #pragma unroll
  for (int st=1; st<64; st<<=1) v += __shfl_xor(v, st);
  return v;
}

// --------- block softmax over 256 values, wave-reduce based (3 barriers) ---------
__device__ __forceinline__ void softmax256f(float val, float* red, float* p){
  int tid=threadIdx.x, wv=tid>>6;
  float m = wred_max(val);
  if ((tid&63)==0) red[wv]=m;
  __syncthreads();
  float mx = fmaxf(fmaxf(red[0],red[1]),fmaxf(red[2],red[3]));
  float ex = __expf(val-mx);
  float s = wred_sum(ex);
  if ((tid&63)==0) red[8+wv]=s;
  __syncthreads();
  float inv = 1.f/(red[8]+red[9]+red[10]+red[11]);
  p[tid]=ex*inv;
  __syncthreads();
}

// ---------------- fused weight conversion (14 segments, K-padding aware) ----------------
struct CvtSeg { const float* src; unsigned short* dst; int rows, Ks, Kd; };
struct CvtArgs { CvtSeg s[14]; };
__global__ void k_cvt_weights(CvtArgs a){
  CvtSeg sg = a.s[blockIdx.y];
  int p = blockIdx.x*256 + threadIdx.x;          // dst pair index
  int Kd2 = sg.Kd>>1;
  int npairs = sg.rows*Kd2;
  if (p >= npairs) return;
  int row = p/Kd2, kk = (p - row*Kd2)*2;
  float f0 = (kk   < sg.Ks)? sg.src[(size_t)row*sg.Ks+kk  ] : 0.f;
  float f1 = (kk+1 < sg.Ks)? sg.src[(size_t)row*sg.Ks+kk+1] : 0.f;
  *(unsigned*)(sg.dst + (size_t)row*sg.Kd + kk) = pack_bf16x2(f0,f1);
}

// ---------------- embedding gather -> padded bf16 ----------------
__global__ void k_embed(const int* __restrict__ inp, const float* __restrict__ emb,
                        unsigned short* __restrict__ xb){
  int row = blockIdx.x;            // b*S+s
  int idx = inp[row];
  const float* src = emb + (size_t)idx*DD;
  unsigned short* dst = xb + (size_t)row*DP;
  int p = threadIdx.x;             // pair index, 152 pairs
  if (p < DP/2){
    float f0 = (2*p   < DD)? src[2*p  ] : 0.f;
    float f1 = (2*p+1 < DD)? src[2*p+1] : 0.f;
    *(unsigned*)(dst + 2*p) = pack_bf16x2(f0,f1);
  }
}

// ---------------- bf16 MFMA matmul, 32x32 tile, dual-job z ----------------
// out[M,N] = X[M,K] @ W[N,K]^T + bias. blockIdx.z selects job {W,bias,out}
// (shared X) so f/b direction pairs run in ONE launch: 2x blocks in flight,
// and 32-row tiles double block count again (latency-bound GEMMs: 0.75 ->
// 3 waves/CU).
__global__ __launch_bounds__(64) void k_mm32(
    const unsigned short* __restrict__ X,
    const unsigned short* __restrict__ W0, const float* __restrict__ b0, float* __restrict__ o0,
    const unsigned short* __restrict__ W1, const float* __restrict__ b1, float* __restrict__ o1,
    int N, int K){
  const unsigned short* W = blockIdx.z? W1 : W0;
  const float* bias       = blockIdx.z? b1 : b0;
  float* out              = blockIdx.z? o1 : o0;
  int lane=threadIdx.x, col=lane&31, half=lane>>5;
  int n0=blockIdx.x*32, m0=blockIdx.y*32;
  const unsigned short* pa = X + (size_t)(m0+col)*K + half*8;
  const unsigned short* pb = W + (size_t)(n0+col)*K + half*8;
  f32x16 acc={};
  #pragma unroll 4
  for (int k=0;k<K;k+=16){
    short8 a=__builtin_bit_cast(short8, *(const uint4*)(pa+k));
    short8 b=__builtin_bit_cast(short8, *(const uint4*)(pb+k));
    acc=__builtin_amdgcn_mfma_f32_32x32x16_bf16(a,b,acc,0,0,0);
  }
  int cn = n0+col;
  float bn = bias? bias[cn] : 0.f;
  #pragma unroll
  for (int r=0;r<16;r++){
    int row=(r&3)+8*(r>>2)+4*half;
    out[(size_t)(m0+row)*N+cn] = acc[r]+bn;
  }
}

// ---------------- GRU scan (one block per (batch, direction)) ----------------
// Round-6-proven structure (188us, 0 bank conflicts): 512 threads = 8 waves,
// readlane h-broadcast (VALU pipes), stride-9 conflict-free partials,
// depth-2 gx prefetch, fused bf16 store(s).
#define GW 8          // dot waves
#define CH 16         // h-chunk per wave = 128/GW
#define PSTR 9        // partial row stride (floats), coprime with 32

__global__ __launch_bounds__(512, 1) void k_gru_scan(
                          const float* __restrict__ gxf, const float* __restrict__ gxb,
                          const float* __restrict__ whhf, const float* __restrict__ whhb,
                          const float* __restrict__ bhhf, const float* __restrict__ bhhb,
                          const float* __restrict__ h0,
                          float* __restrict__ out,
                          unsigned short* __restrict__ out_bf,
                          unsigned short* __restrict__ out_bf2,
                          float* __restrict__ hT){
  int b=blockIdx.x, dir=blockIdx.y, tid=threadIdx.x;
  const float* gx  = dir? gxb : gxf;
  const float* whh = dir? whhb : whhf;
  const float* bhh = dir? bhhb : bhhf;
  int w = tid>>6, lane = tid&63;
  int chunk = w*CH;

  // weights: rows lane+64*(2p), lane+64*(2p+1), chunk slice, packed pairs
  f32x2 wv[3][CH];
  #pragma unroll
  for (int p=0;p<3;p++){
    const float* r0 = whh + (size_t)(lane+64*(2*p  ))*EE + chunk;
    const float* r1 = whh + (size_t)(lane+64*(2*p+1))*EE + chunk;
    #pragma unroll
    for (int k=0;k<CH;k++){ wv[p][k].x = r0[k]; wv[p][k].y = r1[k]; }
  }

  __shared__ __align__(16) float hsh[EE];
  __shared__ float part[H3*PSTR];

  bool comb = (tid < EE);
  float hprev=0.f, b_r=0.f, b_z=0.f, b_n=0.f;
  float xrA=0.f,xzA=0.f,xnA=0.f, xrB=0.f,xzB=0.f,xnB=0.f;
  if (comb){
    int r = tid;
    b_r = bhh[r]; b_z = bhh[r+EE]; b_n = bhh[r+2*EE];
    hprev = h0? h0[((size_t)dir*BB+b)*EE + r] : 0.f;
    hsh[r] = hprev;
    int s0 = dir? (SS-1) : 0;
    int s1 = dir? (SS-2) : 1;
    const float* g0 = gx + ((size_t)b*SS+s0)*H3;
    const float* g1 = gx + ((size_t)b*SS+s1)*H3;
    xrA=g0[r]; xzA=g0[r+EE]; xnA=g0[r+2*EE];
    xrB=g1[r]; xzB=g1[r+EE]; xnB=g1[r+2*EE];
  }
  __syncthreads();

  auto dotphase = [&](){
    float vh = hsh[chunk + (lane & (CH-1))];   // 1 conflict-free ds_read_b32/wave
    f32x2 acc0={0.f,0.f}, acc1={0.f,0.f}, acc2={0.f,0.f};
    #pragma unroll
    for (int k=0;k<CH;k++){
      float s = __builtin_bit_cast(float,
                  __builtin_amdgcn_readlane(__builtin_bit_cast(int, vh), k));
      acc0 += wv[0][k]*s;
      acc1 += wv[1][k]*s;
      acc2 += wv[2][k]*s;
    }
    part[(lane      )*PSTR + w] = acc0.x;
    part[(lane+ 64  )*PSTR + w] = acc0.y;
    part[(lane+128  )*PSTR + w] = acc1.x;
    part[(lane+192  )*PSTR + w] = acc1.y;
    part[(lane+256  )*PSTR + w] = acc2.x;
    part[(lane+320  )*PSTR + w] = acc2.y;
  };

  auto combphase = [&](int t, float xr, float xz, float xn,
                       float& pxr, float& pxz, float& pxn){
    int r = tid;
    float ar=0.f, az=0.f, an=0.f;
    #pragma unroll
    for (int c=0;c<GW;c++){
      ar += part[(r      )*PSTR+c];
      az += part[(r+128  )*PSTR+c];
      an += part[(r+256  )*PSTR+c];
    }
    int s = dir? (SS-1-t) : t;
    float rg = sigmoidf_(xr + ar + b_r);
    float zg = sigmoidf_(xz + az + b_z);
    float ng = tanh_fast(xn + rg*(an + b_n));
    float h2 = (1.f-zg)*ng + zg*hprev;
    hprev = h2;
    hsh[r] = h2;
    size_t rowi = (size_t)b*SS+s;
    size_t oi = rowi*D2 + (size_t)dir*EE + r;
    out[oi] = h2;
    unsigned short hb = (unsigned short)bf16_rne(h2);
    if (out_bf)  out_bf[oi] = hb;
    if (out_bf2) out_bf2[rowi*D12 + (size_t)dir*EE + r] = hb;
    // depth-2 prefetch: reload this set for t+2 (consumed 2 steps from now)
    if (t+2 < SS){
      int sn = dir? (SS-3-t) : (t+2);
      const float* gn = gx + ((size_t)b*SS+sn)*H3;
      pxr=gn[r]; pxz=gn[r+EE]; pxn=gn[r+2*EE];
    }
  };

  for (int t=0;t<SS;t+=2){
    dotphase();
    __syncthreads();
    if (comb) combphase(t, xrA,xzA,xnA, xrA,xzA,xnA);
    __syncthreads();
    dotphase();
    __syncthreads();
    if (comb) combphase(t+1, xrB,xzB,xnB, xrB,xzB,xnB);
    __syncthreads();
  }
  if (hT && comb) hT[((size_t)dir*BB+b)*EE+tid]=hprev;
}

// ------- fused cheap attentions ptc/ptm/ptb: shared PV over hp, bf16 out -------
// s1Am: [M][256] = [s1 | Am] (hp @ [Wc1|Wm]^T), s2BS: [M][384] = [s2 | Bm | spj].
__global__ __launch_bounds__(256) void k_attn3(
    const float* __restrict__ s1Am, const float* __restrict__ s2BS,
    const float* __restrict__ Pb, const float* __restrict__ hq,
    const float* __restrict__ vc, const float* __restrict__ vm,
    const float* __restrict__ V, unsigned short* __restrict__ aggout){
  __shared__ __align__(16) float bq[EE];
  __shared__ __align__(16) float bm[EE];
  __shared__ __align__(16) float vvc[EE];
  __shared__ __align__(16) float vvm[EE];
  __shared__ __align__(16) float hqq[D2];
  __shared__ float pc[SS]; __shared__ float pm[SS]; __shared__ float pbl[SS];
  __shared__ float red[32];
  int q=blockIdx.x, b=blockIdx.y, tid=threadIdx.x;
  size_t bS=(size_t)b*SS;
  if (tid<EE){
    const float* qrow = s2BS + (bS+q)*384;
    bq[tid]=qrow[tid]; bm[tid]=qrow[EE+tid];
    vvc[tid]=vc[tid];  vvm[tid]=vm[tid];
  }
  hqq[tid]=hq[(bS+q)*D2+tid];
  __syncthreads();

  const float* kr = s1Am + (bS+tid)*(size_t)256;
  float sc=0.f, sm=0.f;
  #pragma unroll
  for (int e=0;e<EE;e+=4){
    float4 a1=*(const float4*)(kr+e);
    float4 am=*(const float4*)(kr+EE+e);
    float4 b1=*(const float4*)(bq+e);
    float4 b2=*(const float4*)(bm+e);
    float4 wc=*(const float4*)(vvc+e);
    float4 wm=*(const float4*)(vvm+e);
    sc += wc.x*tanh_fast(a1.x+b1.x)+wc.y*tanh_fast(a1.y+b1.y)
        + wc.z*tanh_fast(a1.z+b1.z)+wc.w*tanh_fast(a1.w+b1.w);
    sm += wm.x*tanh_fast(am.x-b2.x)+wm.y*tanh_fast(am.y-b2.y)
        + wm.z*tanh_fast(am.z-b2.z)+wm.w*tanh_fast(am.w-b2.w);
  }
  float sb=0.f;
  const float* Pr = Pb + (bS+tid)*(size_t)D2;
  #pragma unroll
  for (int d=0;d<D2;d+=4){
    float4 a=*(const float4*)(Pr+d);
    float4 hh=*(const float4*)(hqq+d);
    sb += a.x*hh.x+a.y*hh.y+a.z*hh.z+a.w*hh.w;
  }

  // fused triple softmax (3 barriers)
  int wvid=tid>>6;
  float m1=wred_max(sc), m2=wred_max(sm), m3=wred_max(sb);
  if ((tid&63)==0){ red[wvid]=m1; red[4+wvid]=m2; red[8+wvid]=m3; }
  __syncthreads();
  m1=fmaxf(fmaxf(red[0],red[1]),fmaxf(red[2],red[3]));
  m2=fmaxf(fmaxf(red[4],red[5]),fmaxf(red[6],red[7]));
  m3=fmaxf(fmaxf(red[8],red[9]),fmaxf(red[10],red[11]));
  float e1=__expf(sc-m1), e2=__expf(sm-m2), e3=__expf(sb-m3);
  float t1=wred_sum(e1), t2=wred_sum(e2), t3=wred_sum(e3);
  if ((tid&63)==0){ red[16+wvid]=t1; red[20+wvid]=t2; red[24+wvid]=t3; }
  __syncthreads();
  pc[tid] =e1/(red[16]+red[17]+red[18]+red[19]);
  pm[tid] =e2/(red[20]+red[21]+red[22]+red[23]);
  pbl[tid]=e3/(red[24]+red[25]+red[26]+red[27]);
  __syncthreads();

  // shared PV: one V load feeds 3 accumulators
  const float* V0 = V + bS*D2;
  float oc=0.f, om=0.f, ob=0.f;
  for (int k=0;k<SS;k++){
    float v=V0[(size_t)k*D2+tid];
    oc+=pc[k]*v; om+=pm[k]*v; ob+=pbl[k]*v;
  }
  unsigned short* ao = aggout + (bS+q)*(size_t)D12;
  ao[512 +tid]=(unsigned short)bf16_rne(oc);
  ao[1280+tid]=(unsigned short)bf16_rne(om);
  ao[1024+tid]=(unsigned short)bf16_rne(ob);
}

// ------- fused ptd/pts: MFMA scores + tanh/v reduce + softmax + PV, bf16 out -------
__global__ __launch_bounds__(256, 2) void k_mulattn_fused(
    const unsigned short* __restrict__ keysb,
    const float* __restrict__ qm,
    const unsigned short* __restrict__ Wb,
    const float* __restrict__ v,
    const float* __restrict__ V,
    unsigned short* __restrict__ aggout, int off){
  __shared__ __align__(16) float qrow[D2];
  __shared__ __align__(16) float vrow[EE];
  __shared__ float scq[SS];
  __shared__ float red[16];
  __shared__ float p[SS];
  int q=blockIdx.x, b=blockIdx.y, tid=threadIdx.x;
  int wave=tid>>6, lane=tid&63;
  size_t bS = (size_t)b*SS;
  qrow[tid]=qm[(bS+q)*D2+tid];
  if (tid<EE) vrow[tid]=v[tid];
  __syncthreads();

  f32x16 acc[2][4]={};
  int m0 = wave*64;
  int col = lane&31, half = lane>>5;
  const unsigned short* krow0 = keysb + (bS + m0 + col)*D2 + half*8;
  const unsigned short* krow1 = krow0 + 32*D2;
  const unsigned short* wrow[4];
  #pragma unroll
  for (int n=0;n<4;n++) wrow[n] = Wb + (size_t)(n*32+col)*D2 + half*8;

  for (int d0=0; d0<D2; d0+=16){
    float4 qsA = *(const float4*)&qrow[d0 + half*8];
    float4 qsB = *(const float4*)&qrow[d0 + half*8 + 4];
    short8 bfrag[4];
    #pragma unroll
    for (int n=0;n<4;n++) bfrag[n] = __builtin_bit_cast(short8, *(const uint4*)(wrow[n]+d0));
    #pragma unroll
    for (int i=0;i<2;i++){
      uint4 raw = *(const uint4*)((i? krow1:krow0) + d0);
      float f0=bf16_to_f(raw.x)*qsA.x, f1=bf16hi_to_f(raw.x)*qsA.y;
      float f2=bf16_to_f(raw.y)*qsA.z, f3=bf16hi_to_f(raw.y)*qsA.w;
      float f4=bf16_to_f(raw.z)*qsB.x, f5=bf16hi_to_f(raw.z)*qsB.y;
      float f6=bf16_to_f(raw.w)*qsB.z, f7=bf16hi_to_f(raw.w)*qsB.w;
      uint4 pk;
      pk.x=pack_bf16x2(f0,f1);
      pk.y=pack_bf16x2(f2,f3);
      pk.z=pack_bf16x2(f4,f5);
      pk.w=pack_bf16x2(f6,f7);
      short8 afrag = __builtin_bit_cast(short8, pk);
      #pragma unroll
      for (int n=0;n<4;n++)
        acc[i][n] = __builtin_amdgcn_mfma_f32_32x32x16_bf16(afrag, bfrag[n], acc[i][n], 0,0,0);
    }
  }
  float vn[4];
  #pragma unroll
  for (int n=0;n<4;n++) vn[n]=vrow[n*32+col];
  #pragma unroll
  for (int i=0;i<2;i++){
    #pragma unroll
    for (int r=0;r<16;r++){
      float s = vn[0]*tanh_fast(acc[i][0][r]) + vn[1]*tanh_fast(acc[i][1][r])
              + vn[2]*tanh_fast(acc[i][2][r]) + vn[3]*tanh_fast(acc[i][3][r]);
      s += __shfl_xor(s,1,32); s += __shfl_xor(s,2,32); s += __shfl_xor(s,4,32);
      s += __shfl_xor(s,8,32); s += __shfl_xor(s,16,32);
      int k = m0 + i*32 + (r&3) + 8*(r>>2) + 4*half;
      scq[k] = s;
    }
  }
  __syncthreads();
  float val = scq[tid];
  softmax256f(val, red, p);
  const float* V0 = V + bS*D2;
  float o=0.f;
  for (int k=0;k<SS;k++) o += p[k]*V0[(size_t)k*D2+tid];
  aggout[(bS+q)*D12 + off + tid] = (unsigned short)bf16_rne(o);
}

// ---------------- fused rl pooling + final pooling + prediction ----------------
__global__ __launch_bounds__(256) void k_rl_final(
    const float* __restrict__ s2BS, const float* __restrict__ hq,
    const float* __restrict__ vp, const float* __restrict__ Wc2,
    const float* __restrict__ sA, const float* __restrict__ vc,
    const float* __restrict__ agg_rep, const float* __restrict__ Wpred,
    float* __restrict__ out){
  __shared__ __align__(16) float vpl[EE];
  __shared__ float p[SS]; __shared__ float red[16];
  __shared__ __align__(16) float rr[D2];
  __shared__ __align__(16) float sBl[EE];
  __shared__ __align__(16) float vcl[EE];
  int b=blockIdx.x, tid=threadIdx.x;
  if (tid<EE){ vpl[tid]=vp[tid]; vcl[tid]=vc[tid]; }
  __syncthreads();
  // ---- rl pooling over hq ----
  const float* row = s2BS + ((size_t)b*SS+tid)*384 + 256;
  float sj=0.f;
  #pragma unroll
  for (int e=0;e<EE;e+=4){
    float4 a=*(const float4*)(row+e);
    float4 vw=*(const float4*)(vpl+e);
    sj += vw.x*tanh_fast(a.x)+vw.y*tanh_fast(a.y)+vw.z*tanh_fast(a.z)+vw.w*tanh_fast(a.w);
  }
  softmax256f(sj, red, p);
  float o=0.f;
  for (int s=0;s<SS;s++) o += p[s]*hq[((size_t)b*SS+s)*D2+tid];
  rr[tid]=o; __syncthreads();
  if (tid<EE){
    const float* wr = Wc2 + (size_t)tid*D2;
    float a=0.f;
    #pragma unroll
    for (int d=0;d<D2;d+=4){
      float4 w4=*(const float4*)(wr+d);
      float4 r4=*(const float4*)(rr+d);
      a += w4.x*r4.x+w4.y*r4.y+w4.z*r4.z+w4.w*r4.w;
    }
    sBl[tid]=a;
  }
  __syncthreads();
  // ---- final pooling + prediction ----
  const float* rowA = sA + ((size_t)b*SS+tid)*EE;
  float sc=0.f;
  #pragma unroll
  for (int e=0;e<EE;e+=4){
    float4 a=*(const float4*)(rowA+e);
    float4 bb=*(const float4*)(sBl+e);
    float4 vw=*(const float4*)(vcl+e);
    sc += vw.x*(a.x+bb.x)+vw.y*(a.y+bb.y)+vw.z*(a.z+bb.z)+vw.w*(a.w+bb.w);
  }
  softmax256f(sc, red, p);
  float o2=0.f;
  for (int s=0;s<SS;s++) o2 += p[s]*agg_rep[((size_t)b*SS+s)*D2+tid];
  rr[tid]=o2; __syncthreads();
  if (tid<LL){
    float a=0.f;
    const float* wr = Wpred + (size_t)tid*D2;
    for (int d=0;d<D2;d++) a += wr[d]*rr[d];
    out[(size_t)b*LL+tid]=sigmoidf_(a);
  }
}

extern "C" void kernel_launch(void* const* d_in, const int* in_sizes, int n_in,
                              void* d_out, int out_size, void* d_ws, size_t ws_size,
                              hipStream_t stream){
  (void)in_sizes; (void)n_in; (void)out_size; (void)ws_size;
  const int*   inp = (const int*)d_in[0];
  const float* emb = (const float*)d_in[1];
  const float* enc_wih_f=(const float*)d_in[2],  *enc_whh_f=(const float*)d_in[3],
             *enc_bih_f=(const float*)d_in[4],  *enc_bhh_f=(const float*)d_in[5];
  const float* enc_wih_b=(const float*)d_in[6],  *enc_whh_b=(const float*)d_in[7],
             *enc_bih_b=(const float*)d_in[8],  *enc_bhh_b=(const float*)d_in[9];
  const float* hid_wih_f=(const float*)d_in[10], *hid_whh_f=(const float*)d_in[11],
             *hid_bih_f=(const float*)d_in[12], *hid_bhh_f=(const float*)d_in[13];
  const float* hid_wih_b=(const float*)d_in[14], *hid_whh_b=(const float*)d_in[15],
             *hid_bih_b=(const float*)d_in[16], *hid_bhh_b=(const float*)d_in[17];
  const float* agg_wih_f=(const float*)d_in[18], *agg_whh_f=(const float*)d_in[19],
             *agg_bih_f=(const float*)d_in[20], *agg_bhh_f=(const float*)d_in[21];
  const float* agg_wih_b=(const float*)d_in[22], *agg_whh_b=(const float*)d_in[23],
             *agg_bih_b=(const float*)d_in[24], *agg_bhh_b=(const float*)d_in[25];
  const float* Wc1=(const float*)d_in[26], *Wc2=(const float*)d_in[27], *vc=(const float*)d_in[28];
  const float* Wb =(const float*)d_in[29];
  const float* Wd =(const float*)d_in[30], *vd=(const float*)d_in[31];
  const float* Wm =(const float*)d_in[32], *vm=(const float*)d_in[33];
  const float* Ws =(const float*)d_in[34], *vs=(const float*)d_in[35];
  const float* Wp =(const float*)d_in[36], *vp=(const float*)d_in[37];
  const float* Wpred=(const float*)d_in[38];

  float* ws = (float*)d_ws;
  size_t o = 0;
  float* gxf     = ws + o; o += (size_t)BB*SS*H3;
  float* gxb     = ws + o; o += (size_t)BB*SS*H3;
  float* hp      = ws + o; o += (size_t)BB*SS*D2;
  float* hq      = ws + o; o += (size_t)BB*SS*D2;
  float* hidden  = ws + o; o += (size_t)2*BB*EE;
  float* s1Am    = ws + o; o += (size_t)BB*SS*256;
  float* s2BS    = ws + o; o += (size_t)BB*SS*384;
  float* Pb      = ws + o; o += (size_t)BB*SS*D2;
  float* agg_rep = ws + o; o += (size_t)BB*SS*D2;
  float* sA      = ws + o; o += (size_t)BB*SS*EE;
  // bf16 buffers (ushort counts, all even -> advance o by count/2)
  unsigned short* x_bf      = (unsigned short*)(ws+o); o += (size_t)BB*SS*DP/2;
  unsigned short* hp_bf     = (unsigned short*)(ws+o); o += (size_t)BB*SS*D2/2;
  unsigned short* hq_bf     = (unsigned short*)(ws+o); o += (size_t)BB*SS*D2/2;
  unsigned short* agg_bf    = (unsigned short*)(ws+o); o += (size_t)BB*SS*D12/2;
  unsigned short* aggrep_bf = (unsigned short*)(ws+o); o += (size_t)BB*SS*D2/2;
  unsigned short* encf_bf   = (unsigned short*)(ws+o); o += (size_t)H3*DP/2;
  unsigned short* encb_bf   = (unsigned short*)(ws+o); o += (size_t)H3*DP/2;
  unsigned short* hidf_bf   = (unsigned short*)(ws+o); o += (size_t)H3*D2/2;
  unsigned short* hidb_bf   = (unsigned short*)(ws+o); o += (size_t)H3*D2/2;
  unsigned short* aggf_bf   = (unsigned short*)(ws+o); o += (size_t)H3*D12/2;
  unsigned short* aggb_bf   = (unsigned short*)(ws+o); o += (size_t)H3*D12/2;
  unsigned short* WA_bf     = (unsigned short*)(ws+o); o += (size_t)256*D2/2;  // [Wc1|Wm]
  unsigned short* WB_bf     = (unsigned short*)(ws+o); o += (size_t)384*D2/2;  // [Wc2|Wm|Wp]
  unsigned short* Wb_bf     = (unsigned short*)(ws+o); o += (size_t)D2*D2/2;
  unsigned short* Wd_bf     = (unsigned short*)(ws+o); o += (size_t)EE*D2/2;
  unsigned short* Ws_bf     = (unsigned short*)(ws+o); o += (size_t)EE*D2/2;

  const int M = BB*SS; // 1024
  // dual-job GEMM: one launch per f/b pair (shared X), 32x32 tiles
  auto mm2=[&](const unsigned short* X,
               const unsigned short* W0,const float* b0,float* o0,
               const unsigned short* W1,const float* b1,float* o1,
               int N,int K){
    dim3 g(N/32, M/32, W1? 2:1);
    k_mm32<<<g,64,0,stream>>>(X,W0,b0,o0,W1,b1,o1,N,K);
  };

  // ---- input prep ----
  k_embed<<<M,256,0,stream>>>(inp, emb, x_bf);
  CvtArgs ca;
  ca.s[0]  = {enc_wih_f, encf_bf, H3, DD, DP};
  ca.s[1]  = {enc_wih_b, encb_bf, H3, DD, DP};
  ca.s[2]  = {hid_wih_f, hidf_bf, H3, D2, D2};
  ca.s[3]  = {hid_wih_b, hidb_bf, H3, D2, D2};
  ca.s[4]  = {agg_wih_f, aggf_bf, H3, D12, D12};
  ca.s[5]  = {agg_wih_b, aggb_bf, H3, D12, D12};
  ca.s[6]  = {Wc1, WA_bf,             EE, D2, D2};
  ca.s[7]  = {Wm,  WA_bf + EE*D2,     EE, D2, D2};
  ca.s[8]  = {Wc2, WB_bf,             EE, D2, D2};
  ca.s[9]  = {Wm,  WB_bf + EE*D2,     EE, D2, D2};
  ca.s[10] = {Wp,  WB_bf + 2*EE*D2,   EE, D2, D2};
  ca.s[11] = {Wb,  Wb_bf, D2, D2, D2};
  ca.s[12] = {Wd,  Wd_bf, EE, D2, D2};
  ca.s[13] = {Ws,  Ws_bf, EE, D2, D2};
  {
    int maxpairs = H3*D12/2;  // 294912
    dim3 g((maxpairs+255)/256, 14);
    k_cvt_weights<<<g,256,0,stream>>>(ca);
  }

  // ---- encoder BiGRU (f+b GEMMs in one launch) ----
  mm2(x_bf, encf_bf, enc_bih_f, gxf, encb_bf, enc_bih_b, gxb, H3, DP);
  k_gru_scan<<<dim3(BB,2),512,0,stream>>>(gxf,gxb,enc_whh_f,enc_whh_b,enc_bhh_f,enc_bhh_b,
                                          nullptr,hp,hp_bf,nullptr,hidden);

  // ---- hidden BiGRU (writes hq slice of agg directly) ----
  mm2(hp_bf, hidf_bf, hid_bih_f, gxf, hidb_bf, hid_bih_b, gxb, H3, D2);
  k_gru_scan<<<dim3(BB,2),512,0,stream>>>(gxf,gxb,hid_whh_f,hid_whh_b,hid_bhh_f,hid_bhh_b,
                                          hidden,hq,hq_bf,agg_bf,nullptr);

  // ---- projections: {s1Am, Pb} dual (X=hp), s2BS single (X=hq) ----
  mm2(hp_bf, WA_bf, nullptr, s1Am, Wb_bf, nullptr, Pb, 256, D2);
  mm2(hq_bf, WB_bf, nullptr, s2BS, nullptr, nullptr, nullptr, 384, D2);

  // ---- attentions -> agg (bf16). slices: hq(0) pts(256) ptc(512) ptd(768) ptb(1024) ptm(1280)
  dim3 gq(SS,BB);
  k_attn3<<<gq,256,0,stream>>>(s1Am, s2BS, Pb, hq, vc, vm, hp, agg_bf);
  k_mulattn_fused<<<gq,256,0,stream>>>(hp_bf,hq,Wd_bf,vd,hp,agg_bf,768);
  k_mulattn_fused<<<gq,256,0,stream>>>(hq_bf,hq,Ws_bf,vs,hq,agg_bf,256);

  // ---- aggregation BiGRU ----
  mm2(agg_bf, aggf_bf, agg_bih_f, gxf, aggb_bf, agg_bih_b, gxb, H3, D12);
  k_gru_scan<<<dim3(BB,2),512,0,stream>>>(gxf,gxb,agg_whh_f,agg_whh_b,agg_bhh_f,agg_bhh_b,
                                          nullptr,agg_rep,aggrep_bf,nullptr,nullptr);

  // ---- pooling + prediction ----
  mm2(aggrep_bf, WA_bf, nullptr, sA, nullptr, nullptr, nullptr, EE, D2);  // Wc1 rows of WA
  k_rl_final<<<BB,256,0,stream>>>(s2BS,hq,vp,Wc2,sA,vc,agg_rep,Wpred,(float*)d_out);
}

// Round 9
// 1063.780 us; speedup vs baseline: 1.0638x; 1.0638x over previous
//
#include <hip/hip_runtime.h>
#include <math.h>

#define BB 4
#define SS 256
#define DD 300
#define DP 304   // DD padded to multiple of 16
#define EE 128
#define LL 20
#define H3 384
#define D2 256   // 2E
#define D12 1536 // 12E

typedef __attribute__((ext_vector_type(8)))  short short8;
typedef __attribute__((ext_vector_type(16))) float f32x16;
typedef __attribute__((ext_vector_type(2)))  float f32x2;

__device__ __forceinline__ float tanh_fast(float x){
  float e = __expf(2.f*x);
  return 1.f - 2.f/(e+1.f);
}
__device__ __forceinline__ float sigmoidf_(float x){ return 1.f/(1.f+__expf(-x)); }
__device__ __forceinline__ float bf16_to_f(unsigned u){ return __builtin_bit_cast(float, u<<16); }
__device__ __forceinline__ float bf16hi_to_f(unsigned u){ return __builtin_bit_cast(float, u & 0xFFFF0000u); }
__device__ __forceinline__ unsigned bf16_rne(float f){
  unsigned u = __builtin_bit_cast(unsigned, f);
  return (u + 0x7FFFu + ((u>>16)&1u)) >> 16;
}
__device__ __forceinline__ unsigned pack_bf16x2(float lo, float hi){
  return bf16_rne(lo) | (bf16_rne(hi)<<16);
}

__device__ __forceinline__ float wred_max(float v){
  #pragma unroll
  for (int st=1; st<64; st<<=1) v = fmaxf(v, __shfl_xor(v, st));
  return v;
}
__device__ __forceinline__ float wred_sum(float v){
  #pragma unroll
  for (int st=1; st<64; st<<=1) v += __shfl_xor(v, st);
  return v;
}

// --------- block softmax over 256 values, wave-reduce based (3 barriers) ---------
__device__ __forceinline__ void softmax256f(float val, float* red, float* p){
  int tid=threadIdx.x, wv=tid>>6;
  float m = wred_max(val);
  if ((tid&63)==0) red[wv]=m;
  __syncthreads();
  float mx = fmaxf(fmaxf(red[0],red[1]),fmaxf(red[2],red[3]));
  float ex = __expf(val-mx);
  float s = wred_sum(ex);
  if ((tid&63)==0) red[8+wv]=s;
  __syncthreads();
  float inv = 1.f/(red[8]+red[9]+red[10]+red[11]);
  p[tid]=ex*inv;
  __syncthreads();
}

// ---------------- fused weight conversion (14 segments, K-padding aware) ----------------
struct CvtSeg { const float* src; unsigned short* dst; int rows, Ks, Kd; };
struct CvtArgs { CvtSeg s[14]; };
__global__ void k_cvt_weights(CvtArgs a){
  CvtSeg sg = a.s[blockIdx.y];
  int p = blockIdx.x*256 + threadIdx.x;          // dst pair index
  int Kd2 = sg.Kd>>1;
  int npairs = sg.rows*Kd2;
  if (p >= npairs) return;
  int row = p/Kd2, kk = (p - row*Kd2)*2;
  float f0 = (kk   < sg.Ks)? sg.src[(size_t)row*sg.Ks+kk  ] : 0.f;
  float f1 = (kk+1 < sg.Ks)? sg.src[(size_t)row*sg.Ks+kk+1] : 0.f;
  *(unsigned*)(sg.dst + (size_t)row*sg.Kd + kk) = pack_bf16x2(f0,f1);
}

// ---------------- embedding gather -> padded bf16 ----------------
__global__ void k_embed(const int* __restrict__ inp, const float* __restrict__ emb,
                        unsigned short* __restrict__ xb){
  int row = blockIdx.x;            // b*S+s
  int idx = inp[row];
  const float* src = emb + (size_t)idx*DD;
  unsigned short* dst = xb + (size_t)row*DP;
  int p = threadIdx.x;             // pair index, 152 pairs
  if (p < DP/2){
    float f0 = (2*p   < DD)? src[2*p  ] : 0.f;
    float f1 = (2*p+1 < DD)? src[2*p+1] : 0.f;
    *(unsigned*)(dst + 2*p) = pack_bf16x2(f0,f1);
  }
}

// ---------------- bf16 MFMA matmul, 64x32 tile (r7-proven), dual-job z ----------------
// out[M,N] = X[M,K] @ W[N,K]^T + bias. blockIdx.z selects job {W,bias,out}
// (shared X) so f/b direction pairs run in ONE launch.
__global__ __launch_bounds__(64) void k_mm64(
    const unsigned short* __restrict__ X,
    const unsigned short* __restrict__ W0, const float* __restrict__ b0, float* __restrict__ o0,
    const unsigned short* __restrict__ W1, const float* __restrict__ b1, float* __restrict__ o1,
    int N, int K){
  const unsigned short* W = blockIdx.z? W1 : W0;
  const float* bias       = blockIdx.z? b1 : b0;
  float* out              = blockIdx.z? o1 : o0;
  int lane=threadIdx.x, col=lane&31, half=lane>>5;
  int n0=blockIdx.x*32, m0=blockIdx.y*64;
  const unsigned short* pa0 = X + (size_t)(m0+col)*K + half*8;
  const unsigned short* pa1 = pa0 + (size_t)32*K;
  const unsigned short* pb  = W + (size_t)(n0+col)*K + half*8;
  f32x16 acc0={}, acc1={};
  #pragma unroll 2
  for (int k=0;k<K;k+=16){
    short8 a0=__builtin_bit_cast(short8, *(const uint4*)(pa0+k));
    short8 a1=__builtin_bit_cast(short8, *(const uint4*)(pa1+k));
    short8 bv=__builtin_bit_cast(short8, *(const uint4*)(pb +k));
    acc0=__builtin_amdgcn_mfma_f32_32x32x16_bf16(a0,bv,acc0,0,0,0);
    acc1=__builtin_amdgcn_mfma_f32_32x32x16_bf16(a1,bv,acc1,0,0,0);
  }
  int cn = n0+col;
  float bn = bias? bias[cn] : 0.f;
  #pragma unroll
  for (int r=0;r<16;r++){
    int row=(r&3)+8*(r>>2)+4*half;
    out[(size_t)(m0+row)*N+cn]    = acc0[r]+bn;
    out[(size_t)(m0+32+row)*N+cn] = acc1[r]+bn;
  }
}

// ---------------- GRU scan (one block per (batch, direction)) ----------------
// Round-6 structure (readlane h-broadcast, stride-9 conflict-free partials,
// depth-2 gx prefetch, fused bf16 store). Round-9: the in-loop barriers are
// RAW (sched_barrier + s_waitcnt lgkmcnt(0) + s_barrier) — __syncthreads()
// would drain vmcnt(0), forcing every step to wait for its just-issued gx
// prefetch loads (~200-400cy L2) and out-store acks. All cross-thread
// traffic in the loop is LDS (hsh, part), so lgkm-only ordering is correct;
// global loads/stores float across steps with compiler-counted waits at use.
#define GW 8          // dot waves
#define CH 16         // h-chunk per wave = 128/GW
#define PSTR 9        // partial row stride (floats), coprime with 32

#define RAWBAR() do{ \
  __builtin_amdgcn_sched_barrier(0); \
  asm volatile("s_waitcnt lgkmcnt(0)" ::: "memory"); \
  __builtin_amdgcn_s_barrier(); \
  __builtin_amdgcn_sched_barrier(0); \
}while(0)

__global__ __launch_bounds__(512, 1) void k_gru_scan(
                          const float* __restrict__ gxf, const float* __restrict__ gxb,
                          const float* __restrict__ whhf, const float* __restrict__ whhb,
                          const float* __restrict__ bhhf, const float* __restrict__ bhhb,
                          const float* __restrict__ h0,
                          float* __restrict__ out,
                          unsigned short* __restrict__ out_bf,
                          unsigned short* __restrict__ out_bf2,
                          float* __restrict__ hT){
  int b=blockIdx.x, dir=blockIdx.y, tid=threadIdx.x;
  const float* gx  = dir? gxb : gxf;
  const float* whh = dir? whhb : whhf;
  const float* bhh = dir? bhhb : bhhf;
  int w = tid>>6, lane = tid&63;
  int chunk = w*CH;

  // weights: rows lane+64*(2p), lane+64*(2p+1), chunk slice, packed pairs
  f32x2 wv[3][CH];
  #pragma unroll
  for (int p=0;p<3;p++){
    const float* r0 = whh + (size_t)(lane+64*(2*p  ))*EE + chunk;
    const float* r1 = whh + (size_t)(lane+64*(2*p+1))*EE + chunk;
    #pragma unroll
    for (int k=0;k<CH;k++){ wv[p][k].x = r0[k]; wv[p][k].y = r1[k]; }
  }

  __shared__ __align__(16) float hsh[EE];
  __shared__ float part[H3*PSTR];

  bool comb = (tid < EE);
  float hprev=0.f, b_r=0.f, b_z=0.f, b_n=0.f;
  float xrA=0.f,xzA=0.f,xnA=0.f, xrB=0.f,xzB=0.f,xnB=0.f;
  if (comb){
    int r = tid;
    b_r = bhh[r]; b_z = bhh[r+EE]; b_n = bhh[r+2*EE];
    hprev = h0? h0[((size_t)dir*BB+b)*EE + r] : 0.f;
    hsh[r] = hprev;
    int s0 = dir? (SS-1) : 0;
    int s1 = dir? (SS-2) : 1;
    const float* g0 = gx + ((size_t)b*SS+s0)*H3;
    const float* g1 = gx + ((size_t)b*SS+s1)*H3;
    xrA=g0[r]; xzA=g0[r+EE]; xnA=g0[r+2*EE];
    xrB=g1[r]; xzB=g1[r+EE]; xnB=g1[r+2*EE];
  }
  __syncthreads();

  auto dotphase = [&](){
    float vh = hsh[chunk + (lane & (CH-1))];   // 1 conflict-free ds_read_b32/wave
    f32x2 acc0={0.f,0.f}, acc1={0.f,0.f}, acc2={0.f,0.f};
    #pragma unroll
    for (int k=0;k<CH;k++){
      float s = __builtin_bit_cast(float,
                  __builtin_amdgcn_readlane(__builtin_bit_cast(int, vh), k));
      acc0 += wv[0][k]*s;
      acc1 += wv[1][k]*s;
      acc2 += wv[2][k]*s;
    }
    part[(lane      )*PSTR + w] = acc0.x;
    part[(lane+ 64  )*PSTR + w] = acc0.y;
    part[(lane+128  )*PSTR + w] = acc1.x;
    part[(lane+192  )*PSTR + w] = acc1.y;
    part[(lane+256  )*PSTR + w] = acc2.x;
    part[(lane+320  )*PSTR + w] = acc2.y;
  };

  auto combphase = [&](int t, float xr, float xz, float xn,
                       float& pxr, float& pxz, float& pxn){
    int r = tid;
    float ar=0.f, az=0.f, an=0.f;
    #pragma unroll
    for (int c=0;c<GW;c++){
      ar += part[(r      )*PSTR+c];
      az += part[(r+128  )*PSTR+c];
      an += part[(r+256  )*PSTR+c];
    }
    int s = dir? (SS-1-t) : t;
    float rg = sigmoidf_(xr + ar + b_r);
    float zg = sigmoidf_(xz + az + b_z);
    float ng = tanh_fast(xn + rg*(an + b_n));
    float h2 = (1.f-zg)*ng + zg*hprev;
    hprev = h2;
    hsh[r] = h2;
    size_t rowi = (size_t)b*SS+s;
    size_t oi = rowi*D2 + (size_t)dir*EE + r;
    out[oi] = h2;
    unsigned short hb = (unsigned short)bf16_rne(h2);
    if (out_bf)  out_bf[oi] = hb;
    if (out_bf2) out_bf2[rowi*D12 + (size_t)dir*EE + r] = hb;
    // depth-2 prefetch: reload this set for t+2 (consumed 2 steps from now);
    // with the raw barrier these loads genuinely stay in flight ~2 steps.
    if (t+2 < SS){
      int sn = dir? (SS-3-t) : (t+2);
      const float* gn = gx + ((size_t)b*SS+sn)*H3;
      pxr=gn[r]; pxz=gn[r+EE]; pxn=gn[r+2*EE];
    }
  };

  for (int t=0;t<SS;t+=2){
    dotphase();
    RAWBAR();
    if (comb) combphase(t, xrA,xzA,xnA, xrA,xzA,xnA);
    RAWBAR();
    dotphase();
    RAWBAR();
    if (comb) combphase(t+1, xrB,xzB,xnB, xrB,xzB,xnB);
    RAWBAR();
  }
  if (hT && comb) hT[((size_t)dir*BB+b)*EE+tid]=hprev;
}

// ------- fused cheap attentions ptc/ptm/ptb: shared PV over hp, bf16 out -------
// s1Am: [M][256] = [s1 | Am] (hp @ [Wc1|Wm]^T), s2BS: [M][384] = [s2 | Bm | spj].
__global__ __launch_bounds__(256) void k_attn3(
    const float* __restrict__ s1Am, const float* __restrict__ s2BS,
    const float* __restrict__ Pb, const float* __restrict__ hq,
    const float* __restrict__ vc, const float* __restrict__ vm,
    const float* __restrict__ V, unsigned short* __restrict__ aggout){
  __shared__ __align__(16) float bq[EE];
  __shared__ __align__(16) float bm[EE];
  __shared__ __align__(16) float vvc[EE];
  __shared__ __align__(16) float vvm[EE];
  __shared__ __align__(16) float hqq[D2];
  __shared__ float pc[SS]; __shared__ float pm[SS]; __shared__ float pbl[SS];
  __shared__ float red[32];
  int q=blockIdx.x, b=blockIdx.y, tid=threadIdx.x;
  size_t bS=(size_t)b*SS;
  if (tid<EE){
    const float* qrow = s2BS + (bS+q)*384;
    bq[tid]=qrow[tid]; bm[tid]=qrow[EE+tid];
    vvc[tid]=vc[tid];  vvm[tid]=vm[tid];
  }
  hqq[tid]=hq[(bS+q)*D2+tid];
  __syncthreads();

  const float* kr = s1Am + (bS+tid)*(size_t)256;
  float sc=0.f, sm=0.f;
  #pragma unroll
  for (int e=0;e<EE;e+=4){
    float4 a1=*(const float4*)(kr+e);
    float4 am=*(const float4*)(kr+EE+e);
    float4 b1=*(const float4*)(bq+e);
    float4 b2=*(const float4*)(bm+e);
    float4 wc=*(const float4*)(vvc+e);
    float4 wm=*(const float4*)(vvm+e);
    sc += wc.x*tanh_fast(a1.x+b1.x)+wc.y*tanh_fast(a1.y+b1.y)
        + wc.z*tanh_fast(a1.z+b1.z)+wc.w*tanh_fast(a1.w+b1.w);
    sm += wm.x*tanh_fast(am.x-b2.x)+wm.y*tanh_fast(am.y-b2.y)
        + wm.z*tanh_fast(am.z-b2.z)+wm.w*tanh_fast(am.w-b2.w);
  }
  float sb=0.f;
  const float* Pr = Pb + (bS+tid)*(size_t)D2;
  #pragma unroll
  for (int d=0;d<D2;d+=4){
    float4 a=*(const float4*)(Pr+d);
    float4 hh=*(const float4*)(hqq+d);
    sb += a.x*hh.x+a.y*hh.y+a.z*hh.z+a.w*hh.w;
  }

  // fused triple softmax (3 barriers)
  int wvid=tid>>6;
  float m1=wred_max(sc), m2=wred_max(sm), m3=wred_max(sb);
  if ((tid&63)==0){ red[wvid]=m1; red[4+wvid]=m2; red[8+wvid]=m3; }
  __syncthreads();
  m1=fmaxf(fmaxf(red[0],red[1]),fmaxf(red[2],red[3]));
  m2=fmaxf(fmaxf(red[4],red[5]),fmaxf(red[6],red[7]));
  m3=fmaxf(fmaxf(red[8],red[9]),fmaxf(red[10],red[11]));
  float e1=__expf(sc-m1), e2=__expf(sm-m2), e3=__expf(sb-m3);
  float t1=wred_sum(e1), t2=wred_sum(e2), t3=wred_sum(e3);
  if ((tid&63)==0){ red[16+wvid]=t1; red[20+wvid]=t2; red[24+wvid]=t3; }
  __syncthreads();
  pc[tid] =e1/(red[16]+red[17]+red[18]+red[19]);
  pm[tid] =e2/(red[20]+red[21]+red[22]+red[23]);
  pbl[tid]=e3/(red[24]+red[25]+red[26]+red[27]);
  __syncthreads();

  // shared PV: one V load feeds 3 accumulators
  const float* V0 = V + bS*D2;
  float oc=0.f, om=0.f, ob=0.f;
  for (int k=0;k<SS;k++){
    float v=V0[(size_t)k*D2+tid];
    oc+=pc[k]*v; om+=pm[k]*v; ob+=pbl[k]*v;
  }
  unsigned short* ao = aggout + (bS+q)*(size_t)D12;
  ao[512 +tid]=(unsigned short)bf16_rne(oc);
  ao[1280+tid]=(unsigned short)bf16_rne(om);
  ao[1024+tid]=(unsigned short)bf16_rne(ob);
}

// ------- fused ptd/pts: MFMA scores + tanh/v reduce + softmax + PV, bf16 out -------
__global__ __launch_bounds__(256, 2) void k_mulattn_fused(
    const unsigned short* __restrict__ keysb,
    const float* __restrict__ qm,
    const unsigned short* __restrict__ Wb,
    const float* __restrict__ v,
    const float* __restrict__ V,
    unsigned short* __restrict__ aggout, int off){
  __shared__ __align__(16) float qrow[D2];
  __shared__ __align__(16) float vrow[EE];
  __shared__ float scq[SS];
  __shared__ float red[16];
  __shared__ float p[SS];
  int q=blockIdx.x, b=blockIdx.y, tid=threadIdx.x;
  int wave=tid>>6, lane=tid&63;
  size_t bS = (size_t)b*SS;
  qrow[tid]=qm[(bS+q)*D2+tid];
  if (tid<EE) vrow[tid]=v[tid];
  __syncthreads();

  f32x16 acc[2][4]={};
  int m0 = wave*64;
  int col = lane&31, half = lane>>5;
  const unsigned short* krow0 = keysb + (bS + m0 + col)*D2 + half*8;
  const unsigned short* krow1 = krow0 + 32*D2;
  const unsigned short* wrow[4];
  #pragma unroll
  for (int n=0;n<4;n++) wrow[n] = Wb + (size_t)(n*32+col)*D2 + half*8;

  for (int d0=0; d0<D2; d0+=16){
    float4 qsA = *(const float4*)&qrow[d0 + half*8];
    float4 qsB = *(const float4*)&qrow[d0 + half*8 + 4];
    short8 bfrag[4];
    #pragma unroll
    for (int n=0;n<4;n++) bfrag[n] = __builtin_bit_cast(short8, *(const uint4*)(wrow[n]+d0));
    #pragma unroll
    for (int i=0;i<2;i++){
      uint4 raw = *(const uint4*)((i? krow1:krow0) + d0);
      float f0=bf16_to_f(raw.x)*qsA.x, f1=bf16hi_to_f(raw.x)*qsA.y;
      float f2=bf16_to_f(raw.y)*qsA.z, f3=bf16hi_to_f(raw.y)*qsA.w;
      float f4=bf16_to_f(raw.z)*qsB.x, f5=bf16hi_to_f(raw.z)*qsB.y;
      float f6=bf16_to_f(raw.w)*qsB.z, f7=bf16hi_to_f(raw.w)*qsB.w;
      uint4 pk;
      pk.x=pack_bf16x2(f0,f1);
      pk.y=pack_bf16x2(f2,f3);
      pk.z=pack_bf16x2(f4,f5);
      pk.w=pack_bf16x2(f6,f7);
      short8 afrag = __builtin_bit_cast(short8, pk);
      #pragma unroll
      for (int n=0;n<4;n++)
        acc[i][n] = __builtin_amdgcn_mfma_f32_32x32x16_bf16(afrag, bfrag[n], acc[i][n], 0,0,0);
    }
  }
  float vn[4];
  #pragma unroll
  for (int n=0;n<4;n++) vn[n]=vrow[n*32+col];
  #pragma unroll
  for (int i=0;i<2;i++){
    #pragma unroll
    for (int r=0;r<16;r++){
      float s = vn[0]*tanh_fast(acc[i][0][r]) + vn[1]*tanh_fast(acc[i][1][r])
              + vn[2]*tanh_fast(acc[i][2][r]) + vn[3]*tanh_fast(acc[i][3][r]);
      s += __shfl_xor(s,1,32); s += __shfl_xor(s,2,32); s += __shfl_xor(s,4,32);
      s += __shfl_xor(s,8,32); s += __shfl_xor(s,16,32);
      int k = m0 + i*32 + (r&3) + 8*(r>>2) + 4*half;
      scq[k] = s;
    }
  }
  __syncthreads();
  float val = scq[tid];
  softmax256f(val, red, p);
  const float* V0 = V + bS*D2;
  float o=0.f;
  for (int k=0;k<SS;k++) o += p[k]*V0[(size_t)k*D2+tid];
  aggout[(bS+q)*D12 + off + tid] = (unsigned short)bf16_rne(o);
}

// ---------------- fused rl pooling + final pooling + prediction ----------------
__global__ __launch_bounds__(256) void k_rl_final(
    const float* __restrict__ s2BS, const float* __restrict__ hq,
    const float* __restrict__ vp, const float* __restrict__ Wc2,
    const float* __restrict__ sA, const float* __restrict__ vc,
    const float* __restrict__ agg_rep, const float* __restrict__ Wpred,
    float* __restrict__ out){
  __shared__ __align__(16) float vpl[EE];
  __shared__ float p[SS]; __shared__ float red[16];
  __shared__ __align__(16) float rr[D2];
  __shared__ __align__(16) float sBl[EE];
  __shared__ __align__(16) float vcl[EE];
  int b=blockIdx.x, tid=threadIdx.x;
  if (tid<EE){ vpl[tid]=vp[tid]; vcl[tid]=vc[tid]; }
  __syncthreads();
  // ---- rl pooling over hq ----
  const float* row = s2BS + ((size_t)b*SS+tid)*384 + 256;
  float sj=0.f;
  #pragma unroll
  for (int e=0;e<EE;e+=4){
    float4 a=*(const float4*)(row+e);
    float4 vw=*(const float4*)(vpl+e);
    sj += vw.x*tanh_fast(a.x)+vw.y*tanh_fast(a.y)+vw.z*tanh_fast(a.z)+vw.w*tanh_fast(a.w);
  }
  softmax256f(sj, red, p);
  float o=0.f;
  for (int s=0;s<SS;s++) o += p[s]*hq[((size_t)b*SS+s)*D2+tid];
  rr[tid]=o; __syncthreads();
  if (tid<EE){
    const float* wr = Wc2 + (size_t)tid*D2;
    float a=0.f;
    #pragma unroll
    for (int d=0;d<D2;d+=4){
      float4 w4=*(const float4*)(wr+d);
      float4 r4=*(const float4*)(rr+d);
      a += w4.x*r4.x+w4.y*r4.y+w4.z*r4.z+w4.w*r4.w;
    }
    sBl[tid]=a;
  }
  __syncthreads();
  // ---- final pooling + prediction ----
  const float* rowA = sA + ((size_t)b*SS+tid)*EE;
  float sc=0.f;
  #pragma unroll
  for (int e=0;e<EE;e+=4){
    float4 a=*(const float4*)(rowA+e);
    float4 bb=*(const float4*)(sBl+e);
    float4 vw=*(const float4*)(vcl+e);
    sc += vw.x*(a.x+bb.x)+vw.y*(a.y+bb.y)+vw.z*(a.z+bb.z)+vw.w*(a.w+bb.w);
  }
  softmax256f(sc, red, p);
  float o2=0.f;
  for (int s=0;s<SS;s++) o2 += p[s]*agg_rep[((size_t)b*SS+s)*D2+tid];
  rr[tid]=o2; __syncthreads();
  if (tid<LL){
    float a=0.f;
    const float* wr = Wpred + (size_t)tid*D2;
    for (int d=0;d<D2;d++) a += wr[d]*rr[d];
    out[(size_t)b*LL+tid]=sigmoidf_(a);
  }
}

extern "C" void kernel_launch(void* const* d_in, const int* in_sizes, int n_in,
                              void* d_out, int out_size, void* d_ws, size_t ws_size,
                              hipStream_t stream){
  (void)in_sizes; (void)n_in; (void)out_size; (void)ws_size;
  const int*   inp = (const int*)d_in[0];
  const float* emb = (const float*)d_in[1];
  const float* enc_wih_f=(const float*)d_in[2],  *enc_whh_f=(const float*)d_in[3],
             *enc_bih_f=(const float*)d_in[4],  *enc_bhh_f=(const float*)d_in[5];
  const float* enc_wih_b=(const float*)d_in[6],  *enc_whh_b=(const float*)d_in[7],
             *enc_bih_b=(const float*)d_in[8],  *enc_bhh_b=(const float*)d_in[9];
  const float* hid_wih_f=(const float*)d_in[10], *hid_whh_f=(const float*)d_in[11],
             *hid_bih_f=(const float*)d_in[12], *hid_bhh_f=(const float*)d_in[13];
  const float* hid_wih_b=(const float*)d_in[14], *hid_whh_b=(const float*)d_in[15],
             *hid_bih_b=(const float*)d_in[16], *hid_bhh_b=(const float*)d_in[17];
  const float* agg_wih_f=(const float*)d_in[18], *agg_whh_f=(const float*)d_in[19],
             *agg_bih_f=(const float*)d_in[20], *agg_bhh_f=(const float*)d_in[21];
  const float* agg_wih_b=(const float*)d_in[22], *agg_whh_b=(const float*)d_in[23],
             *agg_bih_b=(const float*)d_in[24], *agg_bhh_b=(const float*)d_in[25];
  const float* Wc1=(const float*)d_in[26], *Wc2=(const float*)d_in[27], *vc=(const float*)d_in[28];
  const float* Wb =(const float*)d_in[29];
  const float* Wd =(const float*)d_in[30], *vd=(const float*)d_in[31];
  const float* Wm =(const float*)d_in[32], *vm=(const float*)d_in[33];
  const float* Ws =(const float*)d_in[34], *vs=(const float*)d_in[35];
  const float* Wp =(const float*)d_in[36], *vp=(const float*)d_in[37];
  const float* Wpred=(const float*)d_in[38];

  float* ws = (float*)d_ws;
  size_t o = 0;
  float* gxf     = ws + o; o += (size_t)BB*SS*H3;
  float* gxb     = ws + o; o += (size_t)BB*SS*H3;
  float* hp      = ws + o; o += (size_t)BB*SS*D2;
  float* hq      = ws + o; o += (size_t)BB*SS*D2;
  float* hidden  = ws + o; o += (size_t)2*BB*EE;
  float* s1Am    = ws + o; o += (size_t)BB*SS*256;
  float* s2BS    = ws + o; o += (size_t)BB*SS*384;
  float* Pb      = ws + o; o += (size_t)BB*SS*D2;
  float* agg_rep = ws + o; o += (size_t)BB*SS*D2;
  float* sA      = ws + o; o += (size_t)BB*SS*EE;
  // bf16 buffers (ushort counts, all even -> advance o by count/2)
  unsigned short* x_bf      = (unsigned short*)(ws+o); o += (size_t)BB*SS*DP/2;
  unsigned short* hp_bf     = (unsigned short*)(ws+o); o += (size_t)BB*SS*D2/2;
  unsigned short* hq_bf     = (unsigned short*)(ws+o); o += (size_t)BB*SS*D2/2;
  unsigned short* agg_bf    = (unsigned short*)(ws+o); o += (size_t)BB*SS*D12/2;
  unsigned short* aggrep_bf = (unsigned short*)(ws+o); o += (size_t)BB*SS*D2/2;
  unsigned short* encf_bf   = (unsigned short*)(ws+o); o += (size_t)H3*DP/2;
  unsigned short* encb_bf   = (unsigned short*)(ws+o); o += (size_t)H3*DP/2;
  unsigned short* hidf_bf   = (unsigned short*)(ws+o); o += (size_t)H3*D2/2;
  unsigned short* hidb_bf   = (unsigned short*)(ws+o); o += (size_t)H3*D2/2;
  unsigned short* aggf_bf   = (unsigned short*)(ws+o); o += (size_t)H3*D12/2;
  unsigned short* aggb_bf   = (unsigned short*)(ws+o); o += (size_t)H3*D12/2;
  unsigned short* WA_bf     = (unsigned short*)(ws+o); o += (size_t)256*D2/2;  // [Wc1|Wm]
  unsigned short* WB_bf     = (unsigned short*)(ws+o); o += (size_t)384*D2/2;  // [Wc2|Wm|Wp]
  unsigned short* Wb_bf     = (unsigned short*)(ws+o); o += (size_t)D2*D2/2;
  unsigned short* Wd_bf     = (unsigned short*)(ws+o); o += (size_t)EE*D2/2;
  unsigned short* Ws_bf     = (unsigned short*)(ws+o); o += (size_t)EE*D2/2;

  const int M = BB*SS; // 1024
  // dual-job GEMM: one launch per f/b pair (shared X), 64x32 tiles
  auto mm2=[&](const unsigned short* X,
               const unsigned short* W0,const float* b0,float* o0,
               const unsigned short* W1,const float* b1,float* o1,
               int N,int K){
    dim3 g(N/32, M/64, W1? 2:1);
    k_mm64<<<g,64,0,stream>>>(X,W0,b0,o0,W1,b1,o1,N,K);
  };

  // ---- input prep ----
  k_embed<<<M,256,0,stream>>>(inp, emb, x_bf);
  CvtArgs ca;
  ca.s[0]  = {enc_wih_f, encf_bf, H3, DD, DP};
  ca.s[1]  = {enc_wih_b, encb_bf, H3, DD, DP};
  ca.s[2]  = {hid_wih_f, hidf_bf, H3, D2, D2};
  ca.s[3]  = {hid_wih_b, hidb_bf, H3, D2, D2};
  ca.s[4]  = {agg_wih_f, aggf_bf, H3, D12, D12};
  ca.s[5]  = {agg_wih_b, aggb_bf, H3, D12, D12};
  ca.s[6]  = {Wc1, WA_bf,             EE, D2, D2};
  ca.s[7]  = {Wm,  WA_bf + EE*D2,     EE, D2, D2};
  ca.s[8]  = {Wc2, WB_bf,             EE, D2, D2};
  ca.s[9]  = {Wm,  WB_bf + EE*D2,     EE, D2, D2};
  ca.s[10] = {Wp,  WB_bf + 2*EE*D2,   EE, D2, D2};
  ca.s[11] = {Wb,  Wb_bf, D2, D2, D2};
  ca.s[12] = {Wd,  Wd_bf, EE, D2, D2};
  ca.s[13] = {Ws,  Ws_bf, EE, D2, D2};
  {
    int maxpairs = H3*D12/2;  // 294912
    dim3 g((maxpairs+255)/256, 14);
    k_cvt_weights<<<g,256,0,stream>>>(ca);
  }

  // ---- encoder BiGRU (f+b GEMMs in one launch) ----
  mm2(x_bf, encf_bf, enc_bih_f, gxf, encb_bf, enc_bih_b, gxb, H3, DP);
  k_gru_scan<<<dim3(BB,2),512,0,stream>>>(gxf,gxb,enc_whh_f,enc_whh_b,enc_bhh_f,enc_bhh_b,
                                          nullptr,hp,hp_bf,nullptr,hidden);

  // ---- hidden BiGRU (writes hq slice of agg directly) ----
  mm2(hp_bf, hidf_bf, hid_bih_f, gxf, hidb_bf, hid_bih_b, gxb, H3, D2);
  k_gru_scan<<<dim3(BB,2),512,0,stream>>>(gxf,gxb,hid_whh_f,hid_whh_b,hid_bhh_f,hid_bhh_b,
                                          hidden,hq,hq_bf,agg_bf,nullptr);

  // ---- projections: {s1Am, Pb} dual (X=hp), s2BS single (X=hq) ----
  mm2(hp_bf, WA_bf, nullptr, s1Am, Wb_bf, nullptr, Pb, 256, D2);
  mm2(hq_bf, WB_bf, nullptr, s2BS, nullptr, nullptr, nullptr, 384, D2);

  // ---- attentions -> agg (bf16). slices: hq(0) pts(256) ptc(512) ptd(768) ptb(1024) ptm(1280)
  dim3 gq(SS,BB);
  k_attn3<<<gq,256,0,stream>>>(s1Am, s2BS, Pb, hq, vc, vm, hp, agg_bf);
  k_mulattn_fused<<<gq,256,0,stream>>>(hp_bf,hq,Wd_bf,vd,hp,agg_bf,768);
  k_mulattn_fused<<<gq,256,0,stream>>>(hq_bf,hq,Ws_bf,vs,hq,agg_bf,256);

  // ---- aggregation BiGRU ----
  mm2(agg_bf, aggf_bf, agg_bih_f, gxf, aggb_bf, agg_bih_b, gxb, H3, D12);
  k_gru_scan<<<dim3(BB,2),512,0,stream>>>(gxf,gxb,agg_whh_f,agg_whh_b,agg_bhh_f,agg_bhh_b,
                                          nullptr,agg_rep,aggrep_bf,nullptr,nullptr);

  // ---- pooling + prediction ----
  mm2(aggrep_bf, WA_bf, nullptr, sA, nullptr, nullptr, nullptr, EE, D2);  // Wc1 rows of WA
  k_rl_final<<<BB,256,0,stream>>>(s2BS,hq,vp,Wc2,sA,vc,agg_rep,Wpred,(float*)d_out);
}

// Round 11
// 1049.417 us; speedup vs baseline: 1.0784x; 1.0137x over previous
//
#include <hip/hip_runtime.h>
#include <math.h>

#define BB 4
#define SS 256
#define DD 300
#define DP 304   // DD padded to multiple of 16
#define EE 128
#define LL 20
#define H3 384
#define D2 256   // 2E
#define D12 1536 // 12E

typedef __attribute__((ext_vector_type(8)))  short short8;
typedef __attribute__((ext_vector_type(16))) float f32x16;
typedef __attribute__((ext_vector_type(2)))  float f32x2;

__device__ __forceinline__ float tanh_fast(float x){
  float e = __expf(2.f*x);
  return 1.f - 2.f/(e+1.f);
}
__device__ __forceinline__ float sigmoidf_(float x){ return 1.f/(1.f+__expf(-x)); }
__device__ __forceinline__ float bf16_to_f(unsigned u){ return __builtin_bit_cast(float, u<<16); }
__device__ __forceinline__ float bf16hi_to_f(unsigned u){ return __builtin_bit_cast(float, u & 0xFFFF0000u); }
__device__ __forceinline__ unsigned bf16_rne(float f){
  unsigned u = __builtin_bit_cast(unsigned, f);
  return (u + 0x7FFFu + ((u>>16)&1u)) >> 16;
}
__device__ __forceinline__ unsigned pack_bf16x2(float lo, float hi){
  return bf16_rne(lo) | (bf16_rne(hi)<<16);
}

__device__ __forceinline__ float wred_max(float v){
  #pragma unroll
  for (int st=1; st<64; st<<=1) v = fmaxf(v, __shfl_xor(v, st));
  return v;
}
__device__ __forceinline__ float wred_sum(float v){
  #pragma unroll
  for (int st=1; st<64; st<<=1) v += __shfl_xor(v, st);
  return v;
}

// --------- block softmax over 256 values, wave-reduce based (3 barriers) ---------
__device__ __forceinline__ void softmax256f(float val, float* red, float* p){
  int tid=threadIdx.x, wv=tid>>6;
  float m = wred_max(val);
  if ((tid&63)==0) red[wv]=m;
  __syncthreads();
  float mx = fmaxf(fmaxf(red[0],red[1]),fmaxf(red[2],red[3]));
  float ex = __expf(val-mx);
  float s = wred_sum(ex);
  if ((tid&63)==0) red[8+wv]=s;
  __syncthreads();
  float inv = 1.f/(red[8]+red[9]+red[10]+red[11]);
  p[tid]=ex*inv;
  __syncthreads();
}

// ------- fused weight conversion + embedding gather (15 segments) -------
// Segment with Ks<0 is the embedding gather: row -> inp[row], stride DD.
struct CvtSeg { const float* src; unsigned short* dst; int rows, Ks, Kd; };
struct CvtArgs { CvtSeg s[15]; const int* inp; };
__global__ void k_cvt_weights(CvtArgs a){
  CvtSeg sg = a.s[blockIdx.y];
  int p = blockIdx.x*256 + threadIdx.x;          // dst pair index
  int Kd2 = sg.Kd>>1;
  int npairs = sg.rows*Kd2;
  if (p >= npairs) return;
  int row = p/Kd2, kk = (p - row*Kd2)*2;
  int eff_Ks = (sg.Ks < 0)? DD : sg.Ks;
  int eff_row = (sg.Ks < 0)? a.inp[row] : row;
  const float* src = sg.src + (size_t)eff_row*eff_Ks;
  float f0 = (kk   < eff_Ks)? src[kk  ] : 0.f;
  float f1 = (kk+1 < eff_Ks)? src[kk+1] : 0.f;
  *(unsigned*)(sg.dst + (size_t)row*sg.Kd + kk) = pack_bf16x2(f0,f1);
}

// ---------------- bf16 MFMA matmul, 64x32 tile, up-to-3-job z ----------------
// out[M,N] = X[M,K] @ W[N,K]^T + bias. blockIdx.z selects a full job
// {X,W,bias,out,N,K}; blocks with n0 >= N exit (jobs may differ in N).
struct MMJob { const unsigned short* X; const unsigned short* W;
               const float* bias; float* out; int N, K; };
struct MMArgs { MMJob j[3]; };
__global__ __launch_bounds__(64) void k_mmN(MMArgs a){
  MMJob jb = a.j[blockIdx.z];
  int n0=blockIdx.x*32;
  if (n0 >= jb.N) return;
  int N = jb.N, K = jb.K;
  int lane=threadIdx.x, col=lane&31, half=lane>>5;
  int m0=blockIdx.y*64;
  const unsigned short* pa0 = jb.X + (size_t)(m0+col)*K + half*8;
  const unsigned short* pa1 = pa0 + (size_t)32*K;
  const unsigned short* pb  = jb.W + (size_t)(n0+col)*K + half*8;
  f32x16 acc0={}, acc1={};
  #pragma unroll 2
  for (int k=0;k<K;k+=16){
    short8 a0=__builtin_bit_cast(short8, *(const uint4*)(pa0+k));
    short8 a1=__builtin_bit_cast(short8, *(const uint4*)(pa1+k));
    short8 bv=__builtin_bit_cast(short8, *(const uint4*)(pb +k));
    acc0=__builtin_amdgcn_mfma_f32_32x32x16_bf16(a0,bv,acc0,0,0,0);
    acc1=__builtin_amdgcn_mfma_f32_32x32x16_bf16(a1,bv,acc1,0,0,0);
  }
  int cn = n0+col;
  float bn = jb.bias? jb.bias[cn] : 0.f;
  #pragma unroll
  for (int r=0;r<16;r++){
    int row=(r&3)+8*(r>>2)+4*half;
    jb.out[(size_t)(m0+row)*N+cn]    = acc0[r]+bn;
    jb.out[(size_t)(m0+32+row)*N+cn] = acc1[r]+bn;
  }
}

// ---------------- GRU scan (one block per (batch, direction)) ----------------
// Round-9-proven (197us, 0 conflicts): 512 threads = 8 waves, readlane
// h-broadcast, stride-9 conflict-free partials, depth-2 gx prefetch,
// fused bf16 stores, raw lgkm-only barriers.
#define GW 8          // dot waves
#define CH 16         // h-chunk per wave = 128/GW
#define PSTR 9        // partial row stride (floats), coprime with 32

#define RAWBAR() do{ \
  __builtin_amdgcn_sched_barrier(0); \
  asm volatile("s_waitcnt lgkmcnt(0)" ::: "memory"); \
  __builtin_amdgcn_s_barrier(); \
  __builtin_amdgcn_sched_barrier(0); \
}while(0)

__global__ __launch_bounds__(512, 1) void k_gru_scan(
                          const float* __restrict__ gxf, const float* __restrict__ gxb,
                          const float* __restrict__ whhf, const float* __restrict__ whhb,
                          const float* __restrict__ bhhf, const float* __restrict__ bhhb,
                          const float* __restrict__ h0,
                          float* __restrict__ out,
                          unsigned short* __restrict__ out_bf,
                          unsigned short* __restrict__ out_bf2,
                          float* __restrict__ hT){
  int b=blockIdx.x, dir=blockIdx.y, tid=threadIdx.x;
  const float* gx  = dir? gxb : gxf;
  const float* whh = dir? whhb : whhf;
  const float* bhh = dir? bhhb : bhhf;
  int w = tid>>6, lane = tid&63;
  int chunk = w*CH;

  f32x2 wv[3][CH];
  #pragma unroll
  for (int p=0;p<3;p++){
    const float* r0 = whh + (size_t)(lane+64*(2*p  ))*EE + chunk;
    const float* r1 = whh + (size_t)(lane+64*(2*p+1))*EE + chunk;
    #pragma unroll
    for (int k=0;k<CH;k++){ wv[p][k].x = r0[k]; wv[p][k].y = r1[k]; }
  }

  __shared__ __align__(16) float hsh[EE];
  __shared__ float part[H3*PSTR];

  bool comb = (tid < EE);
  float hprev=0.f, b_r=0.f, b_z=0.f, b_n=0.f;
  float xrA=0.f,xzA=0.f,xnA=0.f, xrB=0.f,xzB=0.f,xnB=0.f;
  if (comb){
    int r = tid;
    b_r = bhh[r]; b_z = bhh[r+EE]; b_n = bhh[r+2*EE];
    hprev = h0? h0[((size_t)dir*BB+b)*EE + r] : 0.f;
    hsh[r] = hprev;
    int s0 = dir? (SS-1) : 0;
    int s1 = dir? (SS-2) : 1;
    const float* g0 = gx + ((size_t)b*SS+s0)*H3;
    const float* g1 = gx + ((size_t)b*SS+s1)*H3;
    xrA=g0[r]; xzA=g0[r+EE]; xnA=g0[r+2*EE];
    xrB=g1[r]; xzB=g1[r+EE]; xnB=g1[r+2*EE];
  }
  __syncthreads();

  auto dotphase = [&](){
    float vh = hsh[chunk + (lane & (CH-1))];   // 1 conflict-free ds_read_b32/wave
    f32x2 acc0={0.f,0.f}, acc1={0.f,0.f}, acc2={0.f,0.f};
    #pragma unroll
    for (int k=0;k<CH;k++){
      float s = __builtin_bit_cast(float,
                  __builtin_amdgcn_readlane(__builtin_bit_cast(int, vh), k));
      acc0 += wv[0][k]*s;
      acc1 += wv[1][k]*s;
      acc2 += wv[2][k]*s;
    }
    part[(lane      )*PSTR + w] = acc0.x;
    part[(lane+ 64  )*PSTR + w] = acc0.y;
    part[(lane+128  )*PSTR + w] = acc1.x;
    part[(lane+192  )*PSTR + w] = acc1.y;
    part[(lane+256  )*PSTR + w] = acc2.x;
    part[(lane+320  )*PSTR + w] = acc2.y;
  };

  auto combphase = [&](int t, float xr, float xz, float xn,
                       float& pxr, float& pxz, float& pxn){
    int r = tid;
    float ar=0.f, az=0.f, an=0.f;
    #pragma unroll
    for (int c=0;c<GW;c++){
      ar += part[(r      )*PSTR+c];
      az += part[(r+128  )*PSTR+c];
      an += part[(r+256  )*PSTR+c];
    }
    int s = dir? (SS-1-t) : t;
    float rg = sigmoidf_(xr + ar + b_r);
    float zg = sigmoidf_(xz + az + b_z);
    float ng = tanh_fast(xn + rg*(an + b_n));
    float h2 = (1.f-zg)*ng + zg*hprev;
    hprev = h2;
    hsh[r] = h2;
    size_t rowi = (size_t)b*SS+s;
    size_t oi = rowi*D2 + (size_t)dir*EE + r;
    out[oi] = h2;
    unsigned short hb = (unsigned short)bf16_rne(h2);
    if (out_bf)  out_bf[oi] = hb;
    if (out_bf2) out_bf2[rowi*D12 + (size_t)dir*EE + r] = hb;
    if (t+2 < SS){
      int sn = dir? (SS-3-t) : (t+2);
      const float* gn = gx + ((size_t)b*SS+sn)*H3;
      pxr=gn[r]; pxz=gn[r+EE]; pxn=gn[r+2*EE];
    }
  };

  for (int t=0;t<SS;t+=2){
    dotphase();
    RAWBAR();
    if (comb) combphase(t, xrA,xzA,xnA, xrA,xzA,xnA);
    RAWBAR();
    dotphase();
    RAWBAR();
    if (comb) combphase(t+1, xrB,xzB,xnB, xrB,xzB,xnB);
    RAWBAR();
  }
  if (hT && comb) hT[((size_t)dir*BB+b)*EE+tid]=hprev;
}

// ------- merged attention kernel: z=0 attn3 (ptc/ptm/ptb), z=1 ptd, z=2 pts -------
// All __shared__ hoisted to function scope (defensive: no branch-scope LDS).
__global__ __launch_bounds__(256, 2) void k_attn_all(
    const float* __restrict__ s1Am, const float* __restrict__ s2BS,
    const float* __restrict__ Pb,
    const float* __restrict__ hq, const float* __restrict__ hp,
    const unsigned short* __restrict__ hp_bf, const unsigned short* __restrict__ hq_bf,
    const unsigned short* __restrict__ Wd_bf, const unsigned short* __restrict__ Ws_bf,
    const float* __restrict__ vc, const float* __restrict__ vm,
    const float* __restrict__ vd, const float* __restrict__ vs,
    unsigned short* __restrict__ aggout){
  // z==0 path
  __shared__ __align__(16) float bq[EE];
  __shared__ __align__(16) float bm[EE];
  __shared__ __align__(16) float vvc[EE];
  __shared__ __align__(16) float vvm[EE];
  __shared__ __align__(16) float hqq[D2];
  __shared__ float pc[SS]; __shared__ float pm[SS]; __shared__ float pbl[SS];
  __shared__ float red3[32];
  // z!=0 path
  __shared__ __align__(16) float qrow[D2];
  __shared__ __align__(16) float vrow[EE];
  __shared__ float scq[SS];
  __shared__ float red[16];
  __shared__ float p[SS];

  int q=blockIdx.x, b=blockIdx.y, tid=threadIdx.x;
  size_t bS=(size_t)b*SS;

  if (blockIdx.z==0){
    // ---- attn3: ptc/ptm/ptb with shared PV over hp ----
    if (tid<EE){
      const float* qr = s2BS + (bS+q)*384;
      bq[tid]=qr[tid]; bm[tid]=qr[EE+tid];
      vvc[tid]=vc[tid];  vvm[tid]=vm[tid];
    }
    hqq[tid]=hq[(bS+q)*D2+tid];
    __syncthreads();

    const float* kr = s1Am + (bS+tid)*(size_t)256;
    float sc=0.f, sm=0.f;
    #pragma unroll
    for (int e=0;e<EE;e+=4){
      float4 a1=*(const float4*)(kr+e);
      float4 am=*(const float4*)(kr+EE+e);
      float4 b1=*(const float4*)(bq+e);
      float4 b2=*(const float4*)(bm+e);
      float4 wc=*(const float4*)(vvc+e);
      float4 wm=*(const float4*)(vvm+e);
      sc += wc.x*tanh_fast(a1.x+b1.x)+wc.y*tanh_fast(a1.y+b1.y)
          + wc.z*tanh_fast(a1.z+b1.z)+wc.w*tanh_fast(a1.w+b1.w);
      sm += wm.x*tanh_fast(am.x-b2.x)+wm.y*tanh_fast(am.y-b2.y)
          + wm.z*tanh_fast(am.z-b2.z)+wm.w*tanh_fast(am.w-b2.w);
    }
    float sb=0.f;
    const float* Pr = Pb + (bS+tid)*(size_t)D2;
    #pragma unroll
    for (int d=0;d<D2;d+=4){
      float4 a=*(const float4*)(Pr+d);
      float4 hh=*(const float4*)(hqq+d);
      sb += a.x*hh.x+a.y*hh.y+a.z*hh.z+a.w*hh.w;
    }

    int wvid=tid>>6;
    float m1=wred_max(sc), m2=wred_max(sm), m3=wred_max(sb);
    if ((tid&63)==0){ red3[wvid]=m1; red3[4+wvid]=m2; red3[8+wvid]=m3; }
    __syncthreads();
    m1=fmaxf(fmaxf(red3[0],red3[1]),fmaxf(red3[2],red3[3]));
    m2=fmaxf(fmaxf(red3[4],red3[5]),fmaxf(red3[6],red3[7]));
    m3=fmaxf(fmaxf(red3[8],red3[9]),fmaxf(red3[10],red3[11]));
    float e1=__expf(sc-m1), e2=__expf(sm-m2), e3=__expf(sb-m3);
    float t1=wred_sum(e1), t2=wred_sum(e2), t3=wred_sum(e3);
    if ((tid&63)==0){ red3[16+wvid]=t1; red3[20+wvid]=t2; red3[24+wvid]=t3; }
    __syncthreads();
    pc[tid] =e1/(red3[16]+red3[17]+red3[18]+red3[19]);
    pm[tid] =e2/(red3[20]+red3[21]+red3[22]+red3[23]);
    pbl[tid]=e3/(red3[24]+red3[25]+red3[26]+red3[27]);
    __syncthreads();

    const float* V0 = hp + bS*D2;
    float oc=0.f, om=0.f, ob=0.f;
    for (int k=0;k<SS;k++){
      float v=V0[(size_t)k*D2+tid];
      oc+=pc[k]*v; om+=pm[k]*v; ob+=pbl[k]*v;
    }
    unsigned short* ao = aggout + (bS+q)*(size_t)D12;
    ao[512 +tid]=(unsigned short)bf16_rne(oc);
    ao[1280+tid]=(unsigned short)bf16_rne(om);
    ao[1024+tid]=(unsigned short)bf16_rne(ob);
    return;
  }

  // ---- mulattn: z=1 ptd (hp keys/V), z=2 pts (hq keys/V) ----
  const unsigned short* keysb = (blockIdx.z==1)? hp_bf : hq_bf;
  const unsigned short* Wb    = (blockIdx.z==1)? Wd_bf : Ws_bf;
  const float* v              = (blockIdx.z==1)? vd : vs;
  const float* V              = (blockIdx.z==1)? hp : hq;
  int off                     = (blockIdx.z==1)? 768 : 256;

  int wave=tid>>6, lane=tid&63;
  qrow[tid]=hq[(bS+q)*D2+tid];
  if (tid<EE) vrow[tid]=v[tid];
  __syncthreads();

  f32x16 acc[2][4]={};
  int m0 = wave*64;
  int col = lane&31, half = lane>>5;
  const unsigned short* krow0 = keysb + (bS + m0 + col)*D2 + half*8;
  const unsigned short* krow1 = krow0 + 32*D2;
  const unsigned short* wrow[4];
  #pragma unroll
  for (int n=0;n<4;n++) wrow[n] = Wb + (size_t)(n*32+col)*D2 + half*8;

  for (int d0=0; d0<D2; d0+=16){
    float4 qsA = *(const float4*)&qrow[d0 + half*8];
    float4 qsB = *(const float4*)&qrow[d0 + half*8 + 4];
    short8 bfrag[4];
    #pragma unroll
    for (int n=0;n<4;n++) bfrag[n] = __builtin_bit_cast(short8, *(const uint4*)(wrow[n]+d0));
    #pragma unroll
    for (int i=0;i<2;i++){
      uint4 raw = *(const uint4*)((i? krow1:krow0) + d0);
      float f0=bf16_to_f(raw.x)*qsA.x, f1=bf16hi_to_f(raw.x)*qsA.y;
      float f2=bf16_to_f(raw.y)*qsA.z, f3=bf16hi_to_f(raw.y)*qsA.w;
      float f4=bf16_to_f(raw.z)*qsB.x, f5=bf16hi_to_f(raw.z)*qsB.y;
      float f6=bf16_to_f(raw.w)*qsB.z, f7=bf16hi_to_f(raw.w)*qsB.w;
      uint4 pk;
      pk.x=pack_bf16x2(f0,f1);
      pk.y=pack_bf16x2(f2,f3);
      pk.z=pack_bf16x2(f4,f5);
      pk.w=pack_bf16x2(f6,f7);
      short8 afrag = __builtin_bit_cast(short8, pk);
      #pragma unroll
      for (int n=0;n<4;n++)
        acc[i][n] = __builtin_amdgcn_mfma_f32_32x32x16_bf16(afrag, bfrag[n], acc[i][n], 0,0,0);
    }
  }
  float vn[4];
  #pragma unroll
  for (int n=0;n<4;n++) vn[n]=vrow[n*32+col];
  #pragma unroll
  for (int i=0;i<2;i++){
    #pragma unroll
    for (int r=0;r<16;r++){
      float s = vn[0]*tanh_fast(acc[i][0][r]) + vn[1]*tanh_fast(acc[i][1][r])
              + vn[2]*tanh_fast(acc[i][2][r]) + vn[3]*tanh_fast(acc[i][3][r]);
      s += __shfl_xor(s,1,32); s += __shfl_xor(s,2,32); s += __shfl_xor(s,4,32);
      s += __shfl_xor(s,8,32); s += __shfl_xor(s,16,32);
      int k = m0 + i*32 + (r&3) + 8*(r>>2) + 4*half;
      scq[k] = s;
    }
  }
  __syncthreads();
  float val = scq[tid];
  softmax256f(val, red, p);
  const float* V0 = V + bS*D2;
  float o=0.f;
  for (int k=0;k<SS;k++) o += p[k]*V0[(size_t)k*D2+tid];
  aggout[(bS+q)*D12 + off + tid] = (unsigned short)bf16_rne(o);
}

// ---------------- fused rl pooling + final pooling + prediction ----------------
__global__ __launch_bounds__(256) void k_rl_final(
    const float* __restrict__ s2BS, const float* __restrict__ hq,
    const float* __restrict__ vp, const float* __restrict__ Wc2,
    const float* __restrict__ sA, const float* __restrict__ vc,
    const float* __restrict__ agg_rep, const float* __restrict__ Wpred,
    float* __restrict__ out){
  __shared__ __align__(16) float vpl[EE];
  __shared__ float p[SS]; __shared__ float red[16];
  __shared__ __align__(16) float rr[D2];
  __shared__ __align__(16) float sBl[EE];
  __shared__ __align__(16) float vcl[EE];
  int b=blockIdx.x, tid=threadIdx.x;
  if (tid<EE){ vpl[tid]=vp[tid]; vcl[tid]=vc[tid]; }
  __syncthreads();
  // ---- rl pooling over hq ----
  const float* row = s2BS + ((size_t)b*SS+tid)*384 + 256;
  float sj=0.f;
  #pragma unroll
  for (int e=0;e<EE;e+=4){
    float4 a=*(const float4*)(row+e);
    float4 vw=*(const float4*)(vpl+e);
    sj += vw.x*tanh_fast(a.x)+vw.y*tanh_fast(a.y)+vw.z*tanh_fast(a.z)+vw.w*tanh_fast(a.w);
  }
  softmax256f(sj, red, p);
  float o=0.f;
  for (int s=0;s<SS;s++) o += p[s]*hq[((size_t)b*SS+s)*D2+tid];
  rr[tid]=o; __syncthreads();
  if (tid<EE){
    const float* wr = Wc2 + (size_t)tid*D2;
    float a=0.f;
    #pragma unroll
    for (int d=0;d<D2;d+=4){
      float4 w4=*(const float4*)(wr+d);
      float4 r4=*(const float4*)(rr+d);
      a += w4.x*r4.x+w4.y*r4.y+w4.z*r4.z+w4.w*r4.w;
    }
    sBl[tid]=a;
  }
  __syncthreads();
  // ---- final pooling + prediction ----
  const float* rowA = sA + ((size_t)b*SS+tid)*EE;
  float sc=0.f;
  #pragma unroll
  for (int e=0;e<EE;e+=4){
    float4 a=*(const float4*)(rowA+e);
    float4 bb=*(const float4*)(sBl+e);
    float4 vw=*(const float4*)(vcl+e);
    sc += vw.x*(a.x+bb.x)+vw.y*(a.y+bb.y)+vw.z*(a.z+bb.z)+vw.w*(a.w+bb.w);
  }
  softmax256f(sc, red, p);
  float o2=0.f;
  for (int s=0;s<SS;s++) o2 += p[s]*agg_rep[((size_t)b*SS+s)*D2+tid];
  rr[tid]=o2; __syncthreads();
  if (tid<LL){
    float a=0.f;
    const float* wr = Wpred + (size_t)tid*D2;
    for (int d=0;d<D2;d++) a += wr[d]*rr[d];
    out[(size_t)b*LL+tid]=sigmoidf_(a);
  }
}

extern "C" void kernel_launch(void* const* d_in, const int* in_sizes, int n_in,
                              void* d_out, int out_size, void* d_ws, size_t ws_size,
                              hipStream_t stream){
  (void)in_sizes; (void)n_in; (void)out_size; (void)ws_size;
  const int*   inp = (const int*)d_in[0];
  const float* emb = (const float*)d_in[1];
  const float* enc_wih_f=(const float*)d_in[2],  *enc_whh_f=(const float*)d_in[3],
             *enc_bih_f=(const float*)d_in[4],  *enc_bhh_f=(const float*)d_in[5];
  const float* enc_wih_b=(const float*)d_in[6],  *enc_whh_b=(const float*)d_in[7],
             *enc_bih_b=(const float*)d_in[8],  *enc_bhh_b=(const float*)d_in[9];
  const float* hid_wih_f=(const float*)d_in[10], *hid_whh_f=(const float*)d_in[11],
             *hid_bih_f=(const float*)d_in[12], *hid_bhh_f=(const float*)d_in[13];
  const float* hid_wih_b=(const float*)d_in[14], *hid_whh_b=(const float*)d_in[15],
             *hid_bih_b=(const float*)d_in[16], *hid_bhh_b=(const float*)d_in[17];
  const float* agg_wih_f=(const float*)d_in[18], *agg_whh_f=(const float*)d_in[19],
             *agg_bih_f=(const float*)d_in[20], *agg_bhh_f=(const float*)d_in[21];
  const float* agg_wih_b=(const float*)d_in[22], *agg_whh_b=(const float*)d_in[23],
             *agg_bih_b=(const float*)d_in[24], *agg_bhh_b=(const float*)d_in[25];
  const float* Wc1=(const float*)d_in[26], *Wc2=(const float*)d_in[27], *vc=(const float*)d_in[28];
  const float* Wb =(const float*)d_in[29];
  const float* Wd =(const float*)d_in[30], *vd=(const float*)d_in[31];
  const float* Wm =(const float*)d_in[32], *vm=(const float*)d_in[33];
  const float* Ws =(const float*)d_in[34], *vs=(const float*)d_in[35];
  const float* Wp =(const float*)d_in[36], *vp=(const float*)d_in[37];
  const float* Wpred=(const float*)d_in[38];

  float* ws = (float*)d_ws;
  size_t o = 0;
  float* gxf     = ws + o; o += (size_t)BB*SS*H3;
  float* gxb     = ws + o; o += (size_t)BB*SS*H3;
  float* hp      = ws + o; o += (size_t)BB*SS*D2;
  float* hq      = ws + o; o += (size_t)BB*SS*D2;
  float* hidden  = ws + o; o += (size_t)2*BB*EE;
  float* s1Am    = ws + o; o += (size_t)BB*SS*256;
  float* s2BS    = ws + o; o += (size_t)BB*SS*384;
  float* Pb      = ws + o; o += (size_t)BB*SS*D2;
  float* agg_rep = ws + o; o += (size_t)BB*SS*D2;
  float* sA      = ws + o; o += (size_t)BB*SS*EE;
  // bf16 buffers (ushort counts, all even -> advance o by count/2)
  unsigned short* x_bf      = (unsigned short*)(ws+o); o += (size_t)BB*SS*DP/2;
  unsigned short* hp_bf     = (unsigned short*)(ws+o); o += (size_t)BB*SS*D2/2;
  unsigned short* hq_bf     = (unsigned short*)(ws+o); o += (size_t)BB*SS*D2/2;
  unsigned short* agg_bf    = (unsigned short*)(ws+o); o += (size_t)BB*SS*D12/2;
  unsigned short* aggrep_bf = (unsigned short*)(ws+o); o += (size_t)BB*SS*D2/2;
  unsigned short* encf_bf   = (unsigned short*)(ws+o); o += (size_t)H3*DP/2;
  unsigned short* encb_bf   = (unsigned short*)(ws+o); o += (size_t)H3*DP/2;
  unsigned short* hidf_bf   = (unsigned short*)(ws+o); o += (size_t)H3*D2/2;
  unsigned short* hidb_bf   = (unsigned short*)(ws+o); o += (size_t)H3*D2/2;
  unsigned short* aggf_bf   = (unsigned short*)(ws+o); o += (size_t)H3*D12/2;
  unsigned short* aggb_bf   = (unsigned short*)(ws+o); o += (size_t)H3*D12/2;
  unsigned short* WA_bf     = (unsigned short*)(ws+o); o += (size_t)256*D2/2;  // [Wc1|Wm]
  unsigned short* WB_bf     = (unsigned short*)(ws+o); o += (size_t)384*D2/2;  // [Wc2|Wm|Wp]
  unsigned short* Wb_bf     = (unsigned short*)(ws+o); o += (size_t)D2*D2/2;
  unsigned short* Wd_bf     = (unsigned short*)(ws+o); o += (size_t)EE*D2/2;
  unsigned short* Ws_bf     = (unsigned short*)(ws+o); o += (size_t)EE*D2/2;

  const int M = BB*SS; // 1024

  auto mmN=[&](MMJob j0, MMJob j1, MMJob j2, int njobs){
    MMArgs a; a.j[0]=j0; a.j[1]=j1; a.j[2]=j2;
    int maxN = j0.N;
    if (njobs>1 && j1.N>maxN) maxN=j1.N;
    if (njobs>2 && j2.N>maxN) maxN=j2.N;
    dim3 g(maxN/32, M/64, njobs);
    k_mmN<<<g,64,0,stream>>>(a);
  };
  MMJob nil{nullptr,nullptr,nullptr,nullptr,32,16};

  // ---- input prep: weights + embedding in ONE launch ----
  CvtArgs ca;
  ca.inp = inp;
  ca.s[0]  = {enc_wih_f, encf_bf, H3, DD, DP};
  ca.s[1]  = {enc_wih_b, encb_bf, H3, DD, DP};
  ca.s[2]  = {hid_wih_f, hidf_bf, H3, D2, D2};
  ca.s[3]  = {hid_wih_b, hidb_bf, H3, D2, D2};
  ca.s[4]  = {agg_wih_f, aggf_bf, H3, D12, D12};
  ca.s[5]  = {agg_wih_b, aggb_bf, H3, D12, D12};
  ca.s[6]  = {Wc1, WA_bf,             EE, D2, D2};
  ca.s[7]  = {Wm,  WA_bf + EE*D2,     EE, D2, D2};
  ca.s[8]  = {Wc2, WB_bf,             EE, D2, D2};
  ca.s[9]  = {Wm,  WB_bf + EE*D2,     EE, D2, D2};
  ca.s[10] = {Wp,  WB_bf + 2*EE*D2,   EE, D2, D2};
  ca.s[11] = {Wb,  Wb_bf, D2, D2, D2};
  ca.s[12] = {Wd,  Wd_bf, EE, D2, D2};
  ca.s[13] = {Ws,  Ws_bf, EE, D2, D2};
  ca.s[14] = {emb, x_bf,  M,  -1, DP};   // embedding gather segment
  {
    int maxpairs = H3*D12/2;  // 294912
    dim3 g((maxpairs+255)/256, 15);
    k_cvt_weights<<<g,256,0,stream>>>(ca);
  }

  // ---- encoder BiGRU ----
  mmN({x_bf, encf_bf, enc_bih_f, gxf, H3, DP},
      {x_bf, encb_bf, enc_bih_b, gxb, H3, DP}, nil, 2);
  k_gru_scan<<<dim3(BB,2),512,0,stream>>>(gxf,gxb,enc_whh_f,enc_whh_b,enc_bhh_f,enc_bhh_b,
                                          nullptr,hp,hp_bf,nullptr,hidden);

  // ---- hidden BiGRU (writes hq slice of agg directly) ----
  mmN({hp_bf, hidf_bf, hid_bih_f, gxf, H3, D2},
      {hp_bf, hidb_bf, hid_bih_b, gxb, H3, D2}, nil, 2);
  k_gru_scan<<<dim3(BB,2),512,0,stream>>>(gxf,gxb,hid_whh_f,hid_whh_b,hid_bhh_f,hid_bhh_b,
                                          hidden,hq,hq_bf,agg_bf,nullptr);

  // ---- projections: 3 GEMMs in ONE launch (different X per job) ----
  mmN({hp_bf, WA_bf, nullptr, s1Am, 256, D2},
      {hp_bf, Wb_bf, nullptr, Pb,   D2,  D2},
      {hq_bf, WB_bf, nullptr, s2BS, 384, D2}, 3);

  // ---- attentions -> agg (bf16) in ONE launch. slices: hq(0) pts(256) ptc(512) ptd(768) ptb(1024) ptm(1280)
  k_attn_all<<<dim3(SS,BB,3),256,0,stream>>>(s1Am,s2BS,Pb,hq,hp,hp_bf,hq_bf,
                                             Wd_bf,Ws_bf,vc,vm,vd,vs,agg_bf);

  // ---- aggregation BiGRU ----
  mmN({agg_bf, aggf_bf, agg_bih_f, gxf, H3, D12},
      {agg_bf, aggb_bf, agg_bih_b, gxb, H3, D12}, nil, 2);
  k_gru_scan<<<dim3(BB,2),512,0,stream>>>(gxf,gxb,agg_whh_f,agg_whh_b,agg_bhh_f,agg_bhh_b,
                                          nullptr,agg_rep,aggrep_bf,nullptr,nullptr);

  // ---- pooling + prediction ----
  mmN({aggrep_bf, WA_bf, nullptr, sA, EE, D2}, nil, nil, 1);  // Wc1 rows of WA
  k_rl_final<<<BB,256,0,stream>>>(s2BS,hq,vp,Wc2,sA,vc,agg_rep,Wpred,(float*)d_out);
}

// Round 12
// 1042.420 us; speedup vs baseline: 1.0856x; 1.0067x over previous
//
#include <hip/hip_runtime.h>
#include <math.h>

#define BB 4
#define SS 256
#define DD 300
#define DP 304   // DD padded to multiple of 16
#define EE 128
#define LL 20
#define H3 384
#define D2 256   // 2E
#define D12 1536 // 12E

typedef __attribute__((ext_vector_type(8)))  short short8;
typedef __attribute__((ext_vector_type(16))) float f32x16;
typedef __attribute__((ext_vector_type(2)))  float f32x2;

__device__ __forceinline__ float tanh_fast(float x){
  float e = __expf(2.f*x);
  return 1.f - 2.f/(e+1.f);
}
__device__ __forceinline__ float sigmoidf_(float x){ return 1.f/(1.f+__expf(-x)); }
__device__ __forceinline__ float bf16_to_f(unsigned u){ return __builtin_bit_cast(float, u<<16); }
__device__ __forceinline__ float bf16hi_to_f(unsigned u){ return __builtin_bit_cast(float, u & 0xFFFF0000u); }
__device__ __forceinline__ unsigned bf16_rne(float f){
  unsigned u = __builtin_bit_cast(unsigned, f);
  return (u + 0x7FFFu + ((u>>16)&1u)) >> 16;
}
__device__ __forceinline__ unsigned pack_bf16x2(float lo, float hi){
  return bf16_rne(lo) | (bf16_rne(hi)<<16);
}

__device__ __forceinline__ float wred_max(float v){
  #pragma unroll
  for (int st=1; st<64; st<<=1) v = fmaxf(v, __shfl_xor(v, st));
  return v;
}
__device__ __forceinline__ float wred_sum(float v){
  #pragma unroll
  for (int st=1; st<64; st<<=1) v += __shfl_xor(v, st);
  return v;
}

// --------- block softmax over 256 values, wave-reduce based (3 barriers) ---------
__device__ __forceinline__ void softmax256f(float val, float* red, float* p){
  int tid=threadIdx.x, wv=tid>>6;
  float m = wred_max(val);
  if ((tid&63)==0) red[wv]=m;
  __syncthreads();
  float mx = fmaxf(fmaxf(red[0],red[1]),fmaxf(red[2],red[3]));
  float ex = __expf(val-mx);
  float s = wred_sum(ex);
  if ((tid&63)==0) red[8+wv]=s;
  __syncthreads();
  float inv = 1.f/(red[8]+red[9]+red[10]+red[11]);
  p[tid]=ex*inv;
  __syncthreads();
}

// ------- fused weight conversion + embedding gather (15 segments) -------
// Segment with Ks<0 is the embedding gather: row -> inp[row], stride DD.
struct CvtSeg { const float* src; unsigned short* dst; int rows, Ks, Kd; };
struct CvtArgs { CvtSeg s[15]; const int* inp; };
__global__ void k_cvt_weights(CvtArgs a){
  CvtSeg sg = a.s[blockIdx.y];
  int p = blockIdx.x*256 + threadIdx.x;          // dst pair index
  int Kd2 = sg.Kd>>1;
  int npairs = sg.rows*Kd2;
  if (p >= npairs) return;
  int row = p/Kd2, kk = (p - row*Kd2)*2;
  int eff_Ks = (sg.Ks < 0)? DD : sg.Ks;
  int eff_row = (sg.Ks < 0)? a.inp[row] : row;
  const float* src = sg.src + (size_t)eff_row*eff_Ks;
  float f0 = (kk   < eff_Ks)? src[kk  ] : 0.f;
  float f1 = (kk+1 < eff_Ks)? src[kk+1] : 0.f;
  *(unsigned*)(sg.dst + (size_t)row*sg.Kd + kk) = pack_bf16x2(f0,f1);
}

// ---------------- bf16 MFMA matmul, 64x32 tile, up-to-3-job z ----------------
// out[M,N] = X[M,K] @ W[N,K]^T + bias. blockIdx.z selects a full job.
// tr!=0: store transposed PER BATCH: out[b][n][m%256] (b = m/256). The
// uncoalesced stores are cheap (~2K lines/wave, one-shot); they buy fully
// COALESCED score reads in k_attn_all (was 64 lines/instr, the r11 231us
// hot spot).
struct MMJob { const unsigned short* X; const unsigned short* W;
               const float* bias; float* out; int N, K, tr; };
struct MMArgs { MMJob j[3]; };
__global__ __launch_bounds__(64) void k_mmN(MMArgs a){
  MMJob jb = a.j[blockIdx.z];
  int n0=blockIdx.x*32;
  if (n0 >= jb.N) return;
  int N = jb.N, K = jb.K;
  int lane=threadIdx.x, col=lane&31, half=lane>>5;
  int m0=blockIdx.y*64;
  const unsigned short* pa0 = jb.X + (size_t)(m0+col)*K + half*8;
  const unsigned short* pa1 = pa0 + (size_t)32*K;
  const unsigned short* pb  = jb.W + (size_t)(n0+col)*K + half*8;
  f32x16 acc0={}, acc1={};
  #pragma unroll 2
  for (int k=0;k<K;k+=16){
    short8 a0=__builtin_bit_cast(short8, *(const uint4*)(pa0+k));
    short8 a1=__builtin_bit_cast(short8, *(const uint4*)(pa1+k));
    short8 bv=__builtin_bit_cast(short8, *(const uint4*)(pb +k));
    acc0=__builtin_amdgcn_mfma_f32_32x32x16_bf16(a0,bv,acc0,0,0,0);
    acc1=__builtin_amdgcn_mfma_f32_32x32x16_bf16(a1,bv,acc1,0,0,0);
  }
  int cn = n0+col;
  float bn = jb.bias? jb.bias[cn] : 0.f;
  if (jb.tr){
    #pragma unroll
    for (int r=0;r<16;r++){
      int row=(r&3)+8*(r>>2)+4*half;
      int m1=m0+row, m2=m0+32+row;
      jb.out[(size_t)(m1>>8)*((size_t)N*256) + (size_t)cn*256 + (m1&255)] = acc0[r]+bn;
      jb.out[(size_t)(m2>>8)*((size_t)N*256) + (size_t)cn*256 + (m2&255)] = acc1[r]+bn;
    }
  } else {
    #pragma unroll
    for (int r=0;r<16;r++){
      int row=(r&3)+8*(r>>2)+4*half;
      jb.out[(size_t)(m0+row)*N+cn]    = acc0[r]+bn;
      jb.out[(size_t)(m0+32+row)*N+cn] = acc1[r]+bn;
    }
  }
}

// ---------------- GRU scan (one block per (batch, direction)) ----------------
// Round-9-proven (197us, 0 conflicts): 512 threads = 8 waves, readlane
// h-broadcast, stride-9 conflict-free partials, depth-2 gx prefetch,
// fused bf16 stores, raw lgkm-only barriers.
#define GW 8          // dot waves
#define CH 16         // h-chunk per wave = 128/GW
#define PSTR 9        // partial row stride (floats), coprime with 32

#define RAWBAR() do{ \
  __builtin_amdgcn_sched_barrier(0); \
  asm volatile("s_waitcnt lgkmcnt(0)" ::: "memory"); \
  __builtin_amdgcn_s_barrier(); \
  __builtin_amdgcn_sched_barrier(0); \
}while(0)

__global__ __launch_bounds__(512, 1) void k_gru_scan(
                          const float* __restrict__ gxf, const float* __restrict__ gxb,
                          const float* __restrict__ whhf, const float* __restrict__ whhb,
                          const float* __restrict__ bhhf, const float* __restrict__ bhhb,
                          const float* __restrict__ h0,
                          float* __restrict__ out,
                          unsigned short* __restrict__ out_bf,
                          unsigned short* __restrict__ out_bf2,
                          float* __restrict__ hT){
  int b=blockIdx.x, dir=blockIdx.y, tid=threadIdx.x;
  const float* gx  = dir? gxb : gxf;
  const float* whh = dir? whhb : whhf;
  const float* bhh = dir? bhhb : bhhf;
  int w = tid>>6, lane = tid&63;
  int chunk = w*CH;

  f32x2 wv[3][CH];
  #pragma unroll
  for (int p=0;p<3;p++){
    const float* r0 = whh + (size_t)(lane+64*(2*p  ))*EE + chunk;
    const float* r1 = whh + (size_t)(lane+64*(2*p+1))*EE + chunk;
    #pragma unroll
    for (int k=0;k<CH;k++){ wv[p][k].x = r0[k]; wv[p][k].y = r1[k]; }
  }

  __shared__ __align__(16) float hsh[EE];
  __shared__ float part[H3*PSTR];

  bool comb = (tid < EE);
  float hprev=0.f, b_r=0.f, b_z=0.f, b_n=0.f;
  float xrA=0.f,xzA=0.f,xnA=0.f, xrB=0.f,xzB=0.f,xnB=0.f;
  if (comb){
    int r = tid;
    b_r = bhh[r]; b_z = bhh[r+EE]; b_n = bhh[r+2*EE];
    hprev = h0? h0[((size_t)dir*BB+b)*EE + r] : 0.f;
    hsh[r] = hprev;
    int s0 = dir? (SS-1) : 0;
    int s1 = dir? (SS-2) : 1;
    const float* g0 = gx + ((size_t)b*SS+s0)*H3;
    const float* g1 = gx + ((size_t)b*SS+s1)*H3;
    xrA=g0[r]; xzA=g0[r+EE]; xnA=g0[r+2*EE];
    xrB=g1[r]; xzB=g1[r+EE]; xnB=g1[r+2*EE];
  }
  __syncthreads();

  auto dotphase = [&](){
    float vh = hsh[chunk + (lane & (CH-1))];   // 1 conflict-free ds_read_b32/wave
    f32x2 acc0={0.f,0.f}, acc1={0.f,0.f}, acc2={0.f,0.f};
    #pragma unroll
    for (int k=0;k<CH;k++){
      float s = __builtin_bit_cast(float,
                  __builtin_amdgcn_readlane(__builtin_bit_cast(int, vh), k));
      acc0 += wv[0][k]*s;
      acc1 += wv[1][k]*s;
      acc2 += wv[2][k]*s;
    }
    part[(lane      )*PSTR + w] = acc0.x;
    part[(lane+ 64  )*PSTR + w] = acc0.y;
    part[(lane+128  )*PSTR + w] = acc1.x;
    part[(lane+192  )*PSTR + w] = acc1.y;
    part[(lane+256  )*PSTR + w] = acc2.x;
    part[(lane+320  )*PSTR + w] = acc2.y;
  };

  auto combphase = [&](int t, float xr, float xz, float xn,
                       float& pxr, float& pxz, float& pxn){
    int r = tid;
    float ar=0.f, az=0.f, an=0.f;
    #pragma unroll
    for (int c=0;c<GW;c++){
      ar += part[(r      )*PSTR+c];
      az += part[(r+128  )*PSTR+c];
      an += part[(r+256  )*PSTR+c];
    }
    int s = dir? (SS-1-t) : t;
    float rg = sigmoidf_(xr + ar + b_r);
    float zg = sigmoidf_(xz + az + b_z);
    float ng = tanh_fast(xn + rg*(an + b_n));
    float h2 = (1.f-zg)*ng + zg*hprev;
    hprev = h2;
    hsh[r] = h2;
    size_t rowi = (size_t)b*SS+s;
    size_t oi = rowi*D2 + (size_t)dir*EE + r;
    out[oi] = h2;
    unsigned short hb = (unsigned short)bf16_rne(h2);
    if (out_bf)  out_bf[oi] = hb;
    if (out_bf2) out_bf2[rowi*D12 + (size_t)dir*EE + r] = hb;
    if (t+2 < SS){
      int sn = dir? (SS-3-t) : (t+2);
      const float* gn = gx + ((size_t)b*SS+sn)*H3;
      pxr=gn[r]; pxz=gn[r+EE]; pxn=gn[r+2*EE];
    }
  };

  for (int t=0;t<SS;t+=2){
    dotphase();
    RAWBAR();
    if (comb) combphase(t, xrA,xzA,xnA, xrA,xzA,xnA);
    RAWBAR();
    dotphase();
    RAWBAR();
    if (comb) combphase(t+1, xrB,xzB,xnB, xrB,xzB,xnB);
    RAWBAR();
  }
  if (hT && comb) hT[((size_t)dir*BB+b)*EE+tid]=hprev;
}

// ------- merged attention kernel: z=0 attn3 (ptc/ptm/ptb), z=1 ptd, z=2 pts -------
// z=0 score reads are COALESCED via per-batch transposed s1AmT/PbT
// (T[b][col][k], lane=k): 4 lines/instr vs 64 in r11.
__global__ __launch_bounds__(256, 2) void k_attn_all(
    const float* __restrict__ s1AmT, const float* __restrict__ s2BS,
    const float* __restrict__ PbT,
    const float* __restrict__ hq, const float* __restrict__ hp,
    const unsigned short* __restrict__ hp_bf, const unsigned short* __restrict__ hq_bf,
    const unsigned short* __restrict__ Wd_bf, const unsigned short* __restrict__ Ws_bf,
    const float* __restrict__ vc, const float* __restrict__ vm,
    const float* __restrict__ vd, const float* __restrict__ vs,
    unsigned short* __restrict__ aggout){
  // z==0 path
  __shared__ __align__(16) float bq[EE];
  __shared__ __align__(16) float bm[EE];
  __shared__ __align__(16) float vvc[EE];
  __shared__ __align__(16) float vvm[EE];
  __shared__ __align__(16) float hqq[D2];
  __shared__ float pc[SS]; __shared__ float pm[SS]; __shared__ float pbl[SS];
  __shared__ float red3[32];
  // z!=0 path
  __shared__ __align__(16) float qrow[D2];
  __shared__ __align__(16) float vrow[EE];
  __shared__ float scq[SS];
  __shared__ float red[16];
  __shared__ float p[SS];

  int q=blockIdx.x, b=blockIdx.y, tid=threadIdx.x;
  size_t bS=(size_t)b*SS;

  if (blockIdx.z==0){
    // ---- attn3: ptc/ptm/ptb, coalesced transposed score reads ----
    if (tid<EE){
      const float* qr = s2BS + (bS+q)*384;
      bq[tid]=qr[tid]; bm[tid]=qr[EE+tid];
      vvc[tid]=vc[tid];  vvm[tid]=vm[tid];
    }
    hqq[tid]=hq[(bS+q)*D2+tid];
    __syncthreads();

    const float* T1 = s1AmT + (size_t)b*65536;   // [256 cols][256 k]
    const float* TP = PbT   + (size_t)b*65536;   // [256 cols][256 k]
    float sc=0.f, sm=0.f, sb=0.f;
    #pragma unroll 8
    for (int e=0;e<EE;e++){
      float a1 = T1[(size_t)e*256 + tid];        // coalesced
      float am = T1[(size_t)(EE+e)*256 + tid];   // coalesced
      sc += vvc[e]*tanh_fast(a1 + bq[e]);        // bq/vvc: LDS broadcast
      sm += vvm[e]*tanh_fast(am - bm[e]);
    }
    #pragma unroll 8
    for (int d=0;d<D2;d++){
      sb += TP[(size_t)d*256 + tid]*hqq[d];      // coalesced
    }

    int wvid=tid>>6;
    float m1=wred_max(sc), m2=wred_max(sm), m3=wred_max(sb);
    if ((tid&63)==0){ red3[wvid]=m1; red3[4+wvid]=m2; red3[8+wvid]=m3; }
    __syncthreads();
    m1=fmaxf(fmaxf(red3[0],red3[1]),fmaxf(red3[2],red3[3]));
    m2=fmaxf(fmaxf(red3[4],red3[5]),fmaxf(red3[6],red3[7]));
    m3=fmaxf(fmaxf(red3[8],red3[9]),fmaxf(red3[10],red3[11]));
    float e1=__expf(sc-m1), e2=__expf(sm-m2), e3=__expf(sb-m3);
    float t1=wred_sum(e1), t2=wred_sum(e2), t3=wred_sum(e3);
    if ((tid&63)==0){ red3[16+wvid]=t1; red3[20+wvid]=t2; red3[24+wvid]=t3; }
    __syncthreads();
    pc[tid] =e1/(red3[16]+red3[17]+red3[18]+red3[19]);
    pm[tid] =e2/(red3[20]+red3[21]+red3[22]+red3[23]);
    pbl[tid]=e3/(red3[24]+red3[25]+red3[26]+red3[27]);
    __syncthreads();

    const float* V0 = hp + bS*D2;
    float oc=0.f, om=0.f, ob=0.f;
    for (int k=0;k<SS;k++){
      float v=V0[(size_t)k*D2+tid];
      oc+=pc[k]*v; om+=pm[k]*v; ob+=pbl[k]*v;
    }
    unsigned short* ao = aggout + (bS+q)*(size_t)D12;
    ao[512 +tid]=(unsigned short)bf16_rne(oc);
    ao[1280+tid]=(unsigned short)bf16_rne(om);
    ao[1024+tid]=(unsigned short)bf16_rne(ob);
    return;
  }

  // ---- mulattn: z=1 ptd (hp keys/V), z=2 pts (hq keys/V) ----
  const unsigned short* keysb = (blockIdx.z==1)? hp_bf : hq_bf;
  const unsigned short* Wb    = (blockIdx.z==1)? Wd_bf : Ws_bf;
  const float* v              = (blockIdx.z==1)? vd : vs;
  const float* V              = (blockIdx.z==1)? hp : hq;
  int off                     = (blockIdx.z==1)? 768 : 256;

  int wave=tid>>6, lane=tid&63;
  qrow[tid]=hq[(bS+q)*D2+tid];
  if (tid<EE) vrow[tid]=v[tid];
  __syncthreads();

  f32x16 acc[2][4]={};
  int m0 = wave*64;
  int col = lane&31, half = lane>>5;
  const unsigned short* krow0 = keysb + (bS + m0 + col)*D2 + half*8;
  const unsigned short* krow1 = krow0 + 32*D2;
  const unsigned short* wrow[4];
  #pragma unroll
  for (int n=0;n<4;n++) wrow[n] = Wb + (size_t)(n*32+col)*D2 + half*8;

  for (int d0=0; d0<D2; d0+=16){
    float4 qsA = *(const float4*)&qrow[d0 + half*8];
    float4 qsB = *(const float4*)&qrow[d0 + half*8 + 4];
    short8 bfrag[4];
    #pragma unroll
    for (int n=0;n<4;n++) bfrag[n] = __builtin_bit_cast(short8, *(const uint4*)(wrow[n]+d0));
    #pragma unroll
    for (int i=0;i<2;i++){
      uint4 raw = *(const uint4*)((i? krow1:krow0) + d0);
      float f0=bf16_to_f(raw.x)*qsA.x, f1=bf16hi_to_f(raw.x)*qsA.y;
      float f2=bf16_to_f(raw.y)*qsA.z, f3=bf16hi_to_f(raw.y)*qsA.w;
      float f4=bf16_to_f(raw.z)*qsB.x, f5=bf16hi_to_f(raw.z)*qsB.y;
      float f6=bf16_to_f(raw.w)*qsB.z, f7=bf16hi_to_f(raw.w)*qsB.w;
      uint4 pk;
      pk.x=pack_bf16x2(f0,f1);
      pk.y=pack_bf16x2(f2,f3);
      pk.z=pack_bf16x2(f4,f5);
      pk.w=pack_bf16x2(f6,f7);
      short8 afrag = __builtin_bit_cast(short8, pk);
      #pragma unroll
      for (int n=0;n<4;n++)
        acc[i][n] = __builtin_amdgcn_mfma_f32_32x32x16_bf16(afrag, bfrag[n], acc[i][n], 0,0,0);
    }
  }
  float vn[4];
  #pragma unroll
  for (int n=0;n<4;n++) vn[n]=vrow[n*32+col];
  #pragma unroll
  for (int i=0;i<2;i++){
    #pragma unroll
    for (int r=0;r<16;r++){
      float s = vn[0]*tanh_fast(acc[i][0][r]) + vn[1]*tanh_fast(acc[i][1][r])
              + vn[2]*tanh_fast(acc[i][2][r]) + vn[3]*tanh_fast(acc[i][3][r]);
      s += __shfl_xor(s,1,32); s += __shfl_xor(s,2,32); s += __shfl_xor(s,4,32);
      s += __shfl_xor(s,8,32); s += __shfl_xor(s,16,32);
      int k = m0 + i*32 + (r&3) + 8*(r>>2) + 4*half;
      scq[k] = s;
    }
  }
  __syncthreads();
  float val = scq[tid];
  softmax256f(val, red, p);
  const float* V0 = V + bS*D2;
  float o=0.f;
  for (int k=0;k<SS;k++) o += p[k]*V0[(size_t)k*D2+tid];
  aggout[(bS+q)*D12 + off + tid] = (unsigned short)bf16_rne(o);
}

// ---------------- fused rl pooling + final pooling + prediction ----------------
__global__ __launch_bounds__(256) void k_rl_final(
    const float* __restrict__ s2BS, const float* __restrict__ hq,
    const float* __restrict__ vp, const float* __restrict__ Wc2,
    const float* __restrict__ sA, const float* __restrict__ vc,
    const float* __restrict__ agg_rep, const float* __restrict__ Wpred,
    float* __restrict__ out){
  __shared__ __align__(16) float vpl[EE];
  __shared__ float p[SS]; __shared__ float red[16];
  __shared__ __align__(16) float rr[D2];
  __shared__ __align__(16) float sBl[EE];
  __shared__ __align__(16) float vcl[EE];
  int b=blockIdx.x, tid=threadIdx.x;
  if (tid<EE){ vpl[tid]=vp[tid]; vcl[tid]=vc[tid]; }
  __syncthreads();
  // ---- rl pooling over hq ----
  const float* row = s2BS + ((size_t)b*SS+tid)*384 + 256;
  float sj=0.f;
  #pragma unroll
  for (int e=0;e<EE;e+=4){
    float4 a=*(const float4*)(row+e);
    float4 vw=*(const float4*)(vpl+e);
    sj += vw.x*tanh_fast(a.x)+vw.y*tanh_fast(a.y)+vw.z*tanh_fast(a.z)+vw.w*tanh_fast(a.w);
  }
  softmax256f(sj, red, p);
  float o=0.f;
  for (int s=0;s<SS;s++) o += p[s]*hq[((size_t)b*SS+s)*D2+tid];
  rr[tid]=o; __syncthreads();
  if (tid<EE){
    const float* wr = Wc2 + (size_t)tid*D2;
    float a=0.f;
    #pragma unroll
    for (int d=0;d<D2;d+=4){
      float4 w4=*(const float4*)(wr+d);
      float4 r4=*(const float4*)(rr+d);
      a += w4.x*r4.x+w4.y*r4.y+w4.z*r4.z+w4.w*r4.w;
    }
    sBl[tid]=a;
  }
  __syncthreads();
  // ---- final pooling + prediction ----
  const float* rowA = sA + ((size_t)b*SS+tid)*EE;
  float sc=0.f;
  #pragma unroll
  for (int e=0;e<EE;e+=4){
    float4 a=*(const float4*)(rowA+e);
    float4 bb=*(const float4*)(sBl+e);
    float4 vw=*(const float4*)(vcl+e);
    sc += vw.x*(a.x+bb.x)+vw.y*(a.y+bb.y)+vw.z*(a.z+bb.z)+vw.w*(a.w+bb.w);
  }
  softmax256f(sc, red, p);
  float o2=0.f;
  for (int s=0;s<SS;s++) o2 += p[s]*agg_rep[((size_t)b*SS+s)*D2+tid];
  rr[tid]=o2; __syncthreads();
  if (tid<LL){
    float a=0.f;
    const float* wr = Wpred + (size_t)tid*D2;
    for (int d=0;d<D2;d++) a += wr[d]*rr[d];
    out[(size_t)b*LL+tid]=sigmoidf_(a);
  }
}

extern "C" void kernel_launch(void* const* d_in, const int* in_sizes, int n_in,
                              void* d_out, int out_size, void* d_ws, size_t ws_size,
                              hipStream_t stream){
  (void)in_sizes; (void)n_in; (void)out_size; (void)ws_size;
  const int*   inp = (const int*)d_in[0];
  const float* emb = (const float*)d_in[1];
  const float* enc_wih_f=(const float*)d_in[2],  *enc_whh_f=(const float*)d_in[3],
             *enc_bih_f=(const float*)d_in[4],  *enc_bhh_f=(const float*)d_in[5];
  const float* enc_wih_b=(const float*)d_in[6],  *enc_whh_b=(const float*)d_in[7],
             *enc_bih_b=(const float*)d_in[8],  *enc_bhh_b=(const float*)d_in[9];
  const float* hid_wih_f=(const float*)d_in[10], *hid_whh_f=(const float*)d_in[11],
             *hid_bih_f=(const float*)d_in[12], *hid_bhh_f=(const float*)d_in[13];
  const float* hid_wih_b=(const float*)d_in[14], *hid_whh_b=(const float*)d_in[15],
             *hid_bih_b=(const float*)d_in[16], *hid_bhh_b=(const float*)d_in[17];
  const float* agg_wih_f=(const float*)d_in[18], *agg_whh_f=(const float*)d_in[19],
             *agg_bih_f=(const float*)d_in[20], *agg_bhh_f=(const float*)d_in[21];
  const float* agg_wih_b=(const float*)d_in[22], *agg_whh_b=(const float*)d_in[23],
             *agg_bih_b=(const float*)d_in[24], *agg_bhh_b=(const float*)d_in[25];
  const float* Wc1=(const float*)d_in[26], *Wc2=(const float*)d_in[27], *vc=(const float*)d_in[28];
  const float* Wb =(const float*)d_in[29];
  const float* Wd =(const float*)d_in[30], *vd=(const float*)d_in[31];
  const float* Wm =(const float*)d_in[32], *vm=(const float*)d_in[33];
  const float* Ws =(const float*)d_in[34], *vs=(const float*)d_in[35];
  const float* Wp =(const float*)d_in[36], *vp=(const float*)d_in[37];
  const float* Wpred=(const float*)d_in[38];

  float* ws = (float*)d_ws;
  size_t o = 0;
  float* gxf     = ws + o; o += (size_t)BB*SS*H3;
  float* gxb     = ws + o; o += (size_t)BB*SS*H3;
  float* hp      = ws + o; o += (size_t)BB*SS*D2;
  float* hq      = ws + o; o += (size_t)BB*SS*D2;
  float* hidden  = ws + o; o += (size_t)2*BB*EE;
  float* s1AmT   = ws + o; o += (size_t)BB*SS*256;   // transposed per batch
  float* s2BS    = ws + o; o += (size_t)BB*SS*384;
  float* PbT     = ws + o; o += (size_t)BB*SS*D2;    // transposed per batch
  float* agg_rep = ws + o; o += (size_t)BB*SS*D2;
  float* sA      = ws + o; o += (size_t)BB*SS*EE;
  // bf16 buffers (ushort counts, all even -> advance o by count/2)
  unsigned short* x_bf      = (unsigned short*)(ws+o); o += (size_t)BB*SS*DP/2;
  unsigned short* hp_bf     = (unsigned short*)(ws+o); o += (size_t)BB*SS*D2/2;
  unsigned short* hq_bf     = (unsigned short*)(ws+o); o += (size_t)BB*SS*D2/2;
  unsigned short* agg_bf    = (unsigned short*)(ws+o); o += (size_t)BB*SS*D12/2;
  unsigned short* aggrep_bf = (unsigned short*)(ws+o); o += (size_t)BB*SS*D2/2;
  unsigned short* encf_bf   = (unsigned short*)(ws+o); o += (size_t)H3*DP/2;
  unsigned short* encb_bf   = (unsigned short*)(ws+o); o += (size_t)H3*DP/2;
  unsigned short* hidf_bf   = (unsigned short*)(ws+o); o += (size_t)H3*D2/2;
  unsigned short* hidb_bf   = (unsigned short*)(ws+o); o += (size_t)H3*D2/2;
  unsigned short* aggf_bf   = (unsigned short*)(ws+o); o += (size_t)H3*D12/2;
  unsigned short* aggb_bf   = (unsigned short*)(ws+o); o += (size_t)H3*D12/2;
  unsigned short* WA_bf     = (unsigned short*)(ws+o); o += (size_t)256*D2/2;  // [Wc1|Wm]
  unsigned short* WB_bf     = (unsigned short*)(ws+o); o += (size_t)384*D2/2;  // [Wc2|Wm|Wp]
  unsigned short* Wb_bf     = (unsigned short*)(ws+o); o += (size_t)D2*D2/2;
  unsigned short* Wd_bf     = (unsigned short*)(ws+o); o += (size_t)EE*D2/2;
  unsigned short* Ws_bf     = (unsigned short*)(ws+o); o += (size_t)EE*D2/2;

  const int M = BB*SS; // 1024

  auto mmN=[&](MMJob j0, MMJob j1, MMJob j2, int njobs){
    MMArgs a; a.j[0]=j0; a.j[1]=j1; a.j[2]=j2;
    int maxN = j0.N;
    if (njobs>1 && j1.N>maxN) maxN=j1.N;
    if (njobs>2 && j2.N>maxN) maxN=j2.N;
    dim3 g(maxN/32, M/64, njobs);
    k_mmN<<<g,64,0,stream>>>(a);
  };
  MMJob nil{nullptr,nullptr,nullptr,nullptr,32,16,0};

  // ---- input prep: weights + embedding in ONE launch ----
  CvtArgs ca;
  ca.inp = inp;
  ca.s[0]  = {enc_wih_f, encf_bf, H3, DD, DP};
  ca.s[1]  = {enc_wih_b, encb_bf, H3, DD, DP};
  ca.s[2]  = {hid_wih_f, hidf_bf, H3, D2, D2};
  ca.s[3]  = {hid_wih_b, hidb_bf, H3, D2, D2};
  ca.s[4]  = {agg_wih_f, aggf_bf, H3, D12, D12};
  ca.s[5]  = {agg_wih_b, aggb_bf, H3, D12, D12};
  ca.s[6]  = {Wc1, WA_bf,             EE, D2, D2};
  ca.s[7]  = {Wm,  WA_bf + EE*D2,     EE, D2, D2};
  ca.s[8]  = {Wc2, WB_bf,             EE, D2, D2};
  ca.s[9]  = {Wm,  WB_bf + EE*D2,     EE, D2, D2};
  ca.s[10] = {Wp,  WB_bf + 2*EE*D2,   EE, D2, D2};
  ca.s[11] = {Wb,  Wb_bf, D2, D2, D2};
  ca.s[12] = {Wd,  Wd_bf, EE, D2, D2};
  ca.s[13] = {Ws,  Ws_bf, EE, D2, D2};
  ca.s[14] = {emb, x_bf,  M,  -1, DP};   // embedding gather segment
  {
    int maxpairs = H3*D12/2;  // 294912
    dim3 g((maxpairs+255)/256, 15);
    k_cvt_weights<<<g,256,0,stream>>>(ca);
  }

  // ---- encoder BiGRU ----
  mmN({x_bf, encf_bf, enc_bih_f, gxf, H3, DP, 0},
      {x_bf, encb_bf, enc_bih_b, gxb, H3, DP, 0}, nil, 2);
  k_gru_scan<<<dim3(BB,2),512,0,stream>>>(gxf,gxb,enc_whh_f,enc_whh_b,enc_bhh_f,enc_bhh_b,
                                          nullptr,hp,hp_bf,nullptr,hidden);

  // ---- hidden BiGRU (writes hq slice of agg directly) ----
  mmN({hp_bf, hidf_bf, hid_bih_f, gxf, H3, D2, 0},
      {hp_bf, hidb_bf, hid_bih_b, gxb, H3, D2, 0}, nil, 2);
  k_gru_scan<<<dim3(BB,2),512,0,stream>>>(gxf,gxb,hid_whh_f,hid_whh_b,hid_bhh_f,hid_bhh_b,
                                          hidden,hq,hq_bf,agg_bf,nullptr);

  // ---- projections: 3 GEMMs in ONE launch; s1Am and Pb stored TRANSPOSED ----
  mmN({hp_bf, WA_bf, nullptr, s1AmT, 256, D2, 1},
      {hp_bf, Wb_bf, nullptr, PbT,   D2,  D2, 1},
      {hq_bf, WB_bf, nullptr, s2BS,  384, D2, 0}, 3);

  // ---- attentions -> agg (bf16) in ONE launch. slices: hq(0) pts(256) ptc(512) ptd(768) ptb(1024) ptm(1280)
  k_attn_all<<<dim3(SS,BB,3),256,0,stream>>>(s1AmT,s2BS,PbT,hq,hp,hp_bf,hq_bf,
                                             Wd_bf,Ws_bf,vc,vm,vd,vs,agg_bf);

  // ---- aggregation BiGRU ----
  mmN({agg_bf, aggf_bf, agg_bih_f, gxf, H3, D12, 0},
      {agg_bf, aggb_bf, agg_bih_b, gxb, H3, D12, 0}, nil, 2);
  k_gru_scan<<<dim3(BB,2),512,0,stream>>>(gxf,gxb,agg_whh_f,agg_whh_b,agg_bhh_f,agg_bhh_b,
                                          nullptr,agg_rep,aggrep_bf,nullptr,nullptr);

  // ---- pooling + prediction ----
  mmN({aggrep_bf, WA_bf, nullptr, sA, EE, D2, 0}, nil, nil, 1);  // Wc1 rows of WA
  k_rl_final<<<BB,256,0,stream>>>(s2BS,hq,vp,Wc2,sA,vc,agg_rep,Wpred,(float*)d_out);
}